// Round 1
// baseline (1891.357 us; speedup 1.0000x reference)
//
#include <hip/hip_runtime.h>

#define NN 50000
#define EE 800000
#define ET 850000   // EE + NN self loops
#define HH 4
#define CC 64
#define FDIM 256    // HH*CC

// ---------- edge-index dtype handling (int32 vs int64 at runtime) ----------
__device__ __forceinline__ int get_edge(const void* p, int is64, long long idx) {
  if (is64) return (int)((const long long*)p)[idx];
  return ((const int*)p)[idx];
}

__global__ void detect_kernel(const unsigned int* p, int* flag) {
  // If buffer is int64 (values < 50000), every odd 32-bit word (hi half) is 0.
  // For genuine int32 data (random in [0,50000)), 1024 consecutive zeros is impossible.
  unsigned int o = 0;
  for (int i = 1; i < 2048; i += 2) o |= p[i];
  *flag = (o == 0) ? 1 : 0;
}

// ---------- CSR build over dst ----------
__global__ void degree_kernel(const void* eidx, const int* flag, int* deg) {
  int k = blockIdx.x * blockDim.x + threadIdx.x;
  if (k >= ET) return;
  int is64 = *flag;
  int dst = (k < EE) ? get_edge(eidx, is64, (long long)EE + k) : (k - EE);
  atomicAdd(&deg[dst], 1);
}

__global__ __launch_bounds__(1024) void scan_kernel(const int* deg, int* rowptr, int* cursor) {
  __shared__ int partial[1024];
  int t = threadIdx.x;
  const int chunk = (NN + 1023) / 1024;
  int start = t * chunk;
  int end = min(start + chunk, NN);
  int sum = 0;
  for (int i = start; i < end; i++) sum += deg[i];
  partial[t] = sum;
  __syncthreads();
  for (int o = 1; o < 1024; o <<= 1) {
    int v = (t >= o) ? partial[t - o] : 0;
    __syncthreads();
    partial[t] += v;
    __syncthreads();
  }
  int run = (t == 0) ? 0 : partial[t - 1];
  for (int i = start; i < end; i++) {
    rowptr[i] = run; cursor[i] = run; run += deg[i];
  }
  if (t == 1023) rowptr[NN] = partial[1023];
}

__global__ void fill_kernel(const void* eidx, const int* flag, int* cursor, int* eidlist) {
  int k = blockIdx.x * blockDim.x + threadIdx.x;
  if (k >= ET) return;
  int is64 = *flag;
  int dst = (k < EE) ? get_edge(eidx, is64, (long long)EE + k) : (k - EE);
  int pos = atomicAdd(&cursor[dst], 1);
  eidlist[pos] = k;
}

// ---------- fp32 GEMM: C[M,256] = A[M,256] @ B[256,256] ----------
__global__ __launch_bounds__(256) void sgemm_kernel(const float* __restrict__ A,
                                                    const float* __restrict__ B,
                                                    float* __restrict__ C) {
  __shared__ float As[8][128];
  __shared__ float Bs[8][128];
  int t = threadIdx.x;
  int brow0 = blockIdx.x * 128;
  int bcol0 = blockIdx.y * 128;
  int arow = t >> 1;
  int acol = (t & 1) * 4;
  int bk = t >> 5;
  int bc = (t & 31) * 4;
  int tx = t & 15;
  int ty = t >> 4;
  float acc[8][8];
#pragma unroll
  for (int i = 0; i < 8; i++)
#pragma unroll
    for (int j = 0; j < 8; j++) acc[i][j] = 0.f;

  for (int k0 = 0; k0 < 256; k0 += 8) {
    int gr = brow0 + arow;
    float4 a4 = make_float4(0.f, 0.f, 0.f, 0.f);
    if (gr < NN) a4 = *(const float4*)(A + (size_t)gr * 256 + k0 + acol);
    As[acol + 0][arow] = a4.x;
    As[acol + 1][arow] = a4.y;
    As[acol + 2][arow] = a4.z;
    As[acol + 3][arow] = a4.w;
    *(float4*)&Bs[bk][bc] = *(const float4*)(B + (size_t)(k0 + bk) * 256 + bcol0 + bc);
    __syncthreads();
#pragma unroll
    for (int kk = 0; kk < 8; kk++) {
      float ar[8], br[8];
      *(float4*)&ar[0] = *(const float4*)&As[kk][ty * 8];
      *(float4*)&ar[4] = *(const float4*)&As[kk][ty * 8 + 4];
      *(float4*)&br[0] = *(const float4*)&Bs[kk][tx * 8];
      *(float4*)&br[4] = *(const float4*)&Bs[kk][tx * 8 + 4];
#pragma unroll
      for (int i = 0; i < 8; i++)
#pragma unroll
        for (int j = 0; j < 8; j++) acc[i][j] += ar[i] * br[j];
    }
    __syncthreads();
  }
#pragma unroll
  for (int i = 0; i < 8; i++) {
    int gr = brow0 + ty * 8 + i;
    if (gr < NN) {
      *(float4*)(C + (size_t)gr * 256 + bcol0 + tx * 8) =
          make_float4(acc[i][0], acc[i][1], acc[i][2], acc[i][3]);
      *(float4*)(C + (size_t)gr * 256 + bcol0 + tx * 8 + 4) =
          make_float4(acc[i][4], acc[i][5], acc[i][6], acc[i][7]);
    }
  }
}

// ---------- attention logits s,d per (node, head) ----------
__global__ __launch_bounds__(256) void sd_kernel(const float* __restrict__ h,
                                                 const float* __restrict__ as_,
                                                 const float* __restrict__ ad_,
                                                 float* __restrict__ s, float* __restrict__ d) {
  int n = blockIdx.x;
  int wv = threadIdx.x >> 6;
  int lane = threadIdx.x & 63;
  float v = h[(size_t)n * FDIM + wv * CC + lane];
  float ps = v * as_[wv * CC + lane];
  float pd = v * ad_[wv * CC + lane];
#pragma unroll
  for (int o = 32; o > 0; o >>= 1) {
    ps += __shfl_xor(ps, o);
    pd += __shfl_xor(pd, o);
  }
  if (lane == 0) { s[n * HH + wv] = ps; d[n * HH + wv] = pd; }
}

// ---------- unnormalized attention weights per edge (no max needed: shift-invariant) ----------
__global__ void edgew_kernel(const void* eidx, const int* flag,
                             const float* __restrict__ s, const float* __restrict__ d,
                             float* __restrict__ w) {
  int k = blockIdx.x * blockDim.x + threadIdx.x;
  if (k >= ET) return;
  int is64 = *flag;
  int src, dst;
  if (k < EE) {
    src = get_edge(eidx, is64, k);
    dst = get_edge(eidx, is64, (long long)EE + k);
  } else {
    src = dst = k - EE;
  }
  float4 ss = *(const float4*)(s + (size_t)src * 4);
  float4 dd = *(const float4*)(d + (size_t)dst * 4);
  float4 r;
  float t0;
  t0 = ss.x + dd.x; t0 = (t0 > 0.f) ? t0 : 0.2f * t0; r.x = expf(t0);
  t0 = ss.y + dd.y; t0 = (t0 > 0.f) ? t0 : 0.2f * t0; r.y = expf(t0);
  t0 = ss.z + dd.z; t0 = (t0 > 0.f) ? t0 : 0.2f * t0; r.z = expf(t0);
  t0 = ss.w + dd.w; t0 = (t0 > 0.f) ? t0 : 0.2f * t0; r.w = expf(t0);
  *(float4*)(w + (size_t)k * 4) = r;
}

// ---------- aggregation: one block per dst node, one wave per head, lane=channel ----------
template <bool CONCAT>
__global__ __launch_bounds__(256) void agg_kernel(const float* __restrict__ hfeat,
                                                  const float* __restrict__ w,
                                                  const int* __restrict__ rowptr,
                                                  const int* __restrict__ eidlist,
                                                  const void* eidx, const int* flag,
                                                  const float* __restrict__ bias,
                                                  float* __restrict__ outp) {
  __shared__ float tmp[256];
  int n = blockIdx.x;
  int wv = threadIdx.x >> 6;
  int lane = threadIdx.x & 63;
  int is64 = *flag;
  int beg = rowptr[n], end = rowptr[n + 1];
  float acc = 0.f, den = 0.f;
  for (int i = beg; i < end; i++) {
    int eid = eidlist[i];
    int src = (eid < EE) ? get_edge(eidx, is64, eid) : (eid - EE);
    float wval = w[(size_t)eid * 4 + wv];
    den += wval;
    acc += wval * hfeat[(size_t)src * FDIM + wv * CC + lane];
  }
  float res = acc / den;  // every node has a self loop -> den > 0
  if (CONCAT) {
    outp[(size_t)n * FDIM + wv * CC + lane] = res + bias[wv * CC + lane];
  } else {
    tmp[threadIdx.x] = res;
    __syncthreads();
    if (threadIdx.x < 64) {
      float m = 0.25f * (tmp[lane] + tmp[64 + lane] + tmp[128 + lane] + tmp[192 + lane]);
      outp[(size_t)n * CC + lane] = m + bias[lane];
    }
  }
}

// ---------- GraphNorm: single-pass sum/sumsq, then scale/shift, then fused apply+LeakyReLU ----------
__global__ __launch_bounds__(256) void norm_reduce(const float* __restrict__ xin,
                                                   float* colsum, float* colsumsq, int F) {
  int f = threadIdx.x & (F - 1);
  int rl = threadIdx.x / F;
  int rpb = 256 / F;
  int r0 = blockIdx.x * 128;
  int r1 = min(NN, r0 + 128);
  float s1 = 0.f, s2 = 0.f;
  for (int r = r0 + rl; r < r1; r += rpb) {
    float v = xin[(size_t)r * F + f];
    s1 += v;
    s2 += v * v;
  }
  atomicAdd(&colsum[f], s1);
  atomicAdd(&colsumsq[f], s2);
}

__global__ void norm_finalize(const float* colsum, const float* colsumsq,
                              const float* ga, const float* gw, const float* gb,
                              float* nscale, float* nshift, int F) {
  int f = threadIdx.x;
  if (f >= F) return;
  const float invn = 1.0f / (float)NN;
  float mu = colsum[f] * invn;
  float ex2 = colsumsq[f] * invn;
  float a = ga[f];
  // E[(x - a*mu)^2] = E[x^2] - (2a - a^2)*mu^2
  float var = ex2 - (2.f * a - a * a) * mu * mu;
  var = fmaxf(var, 0.f);
  float sc = gw[f] * rsqrtf(var + 1e-5f);
  nscale[f] = sc;
  nshift[f] = gb[f] - sc * a * mu;
}

__global__ void norm_apply(float* xio, const float* __restrict__ nscale,
                           const float* __restrict__ nshift, int F) {
  long long i = (long long)blockIdx.x * 256 + threadIdx.x;
  if (i >= (long long)NN * F) return;
  int f = (int)(i & (F - 1));
  float y = nscale[f] * xio[i] + nshift[f];
  xio[i] = (y > 0.f) ? y : 0.01f * y;  // nn.LeakyReLU default slope
}

// ---------- MLP 64->32->16->2, weights in LDS, one thread per node ----------
__global__ __launch_bounds__(256) void mlp_kernel(const float* __restrict__ xin,
                                                  const float* mW0, const float* mb0,
                                                  const float* mW1, const float* mb1,
                                                  const float* mW2, const float* mb2,
                                                  float* __restrict__ out) {
  __shared__ float W0s[64 * 32];
  __shared__ float W1s[32 * 16];
  __shared__ float W2s[16 * 2];
  __shared__ float b0s[32], b1s[16], b2s[2];
  int t = threadIdx.x;
  for (int i = t; i < 2048; i += 256) W0s[i] = mW0[i];
  for (int i = t; i < 512; i += 256) W1s[i] = mW1[i];
  if (t < 32) { W2s[t] = mW2[t]; b0s[t] = mb0[t]; }
  if (t < 16) b1s[t] = mb1[t];
  if (t < 2) b2s[t] = mb2[t];
  __syncthreads();
  int node = blockIdx.x * 256 + t;
  if (node >= NN) return;
  float in[64];
  const float* xr = xin + (size_t)node * 64;
#pragma unroll
  for (int k = 0; k < 64; k++) in[k] = xr[k];
  float h1[32];
#pragma unroll
  for (int j = 0; j < 32; j++) h1[j] = b0s[j];
#pragma unroll
  for (int k = 0; k < 64; k++) {
    float v = in[k];
#pragma unroll
    for (int j = 0; j < 32; j++) h1[j] += v * W0s[k * 32 + j];
  }
#pragma unroll
  for (int j = 0; j < 32; j++) h1[j] = fmaxf(h1[j], 0.f);
  float h2[16];
#pragma unroll
  for (int j = 0; j < 16; j++) h2[j] = b1s[j];
#pragma unroll
  for (int k = 0; k < 32; k++) {
    float v = h1[k];
#pragma unroll
    for (int j = 0; j < 16; j++) h2[j] += v * W1s[k * 16 + j];
  }
#pragma unroll
  for (int j = 0; j < 16; j++) h2[j] = fmaxf(h2[j], 0.f);
  float o0 = b2s[0], o1 = b2s[1];
#pragma unroll
  for (int k = 0; k < 16; k++) {
    o0 += h2[k] * W2s[k * 2 + 0];
    o1 += h2[k] * W2s[k * 2 + 1];
  }
  out[(size_t)node * 2 + 0] = o0;
  out[(size_t)node * 2 + 1] = o1;
}

extern "C" void kernel_launch(void* const* d_in, const int* in_sizes, int n_in,
                              void* d_out, int out_size, void* d_ws, size_t ws_size,
                              hipStream_t stream) {
  const float* x = (const float*)d_in[0];
  const void* ei = d_in[1];
  const float* W[3]   = {(const float*)d_in[2],  (const float*)d_in[9],  (const float*)d_in[16]};
  const float* as_[3] = {(const float*)d_in[3],  (const float*)d_in[10], (const float*)d_in[17]};
  const float* ad_[3] = {(const float*)d_in[4],  (const float*)d_in[11], (const float*)d_in[18]};
  const float* b_[3]  = {(const float*)d_in[5],  (const float*)d_in[12], (const float*)d_in[19]};
  const float* gw[3]  = {(const float*)d_in[6],  (const float*)d_in[13], (const float*)d_in[20]};
  const float* gb[3]  = {(const float*)d_in[7],  (const float*)d_in[14], (const float*)d_in[21]};
  const float* ga[3]  = {(const float*)d_in[8],  (const float*)d_in[15], (const float*)d_in[22]};
  const float* mW0 = (const float*)d_in[23];
  const float* mb0 = (const float*)d_in[24];
  const float* mW1 = (const float*)d_in[25];
  const float* mb1 = (const float*)d_in[26];
  const float* mW2 = (const float*)d_in[27];
  const float* mb2 = (const float*)d_in[28];
  float* out = (float*)d_out;

  char* ws = (char*)d_ws;
  size_t off = 0;
  auto take = [&](size_t bytes) -> char* {
    char* p = ws + off;
    off = (off + bytes + 255) & ~(size_t)255;
    return p;
  };
  float* bufA    = (float*)take((size_t)NN * FDIM * 4);
  float* bufB    = (float*)take((size_t)NN * FDIM * 4);
  float* bufD    = (float*)take((size_t)NN * CC * 4);
  float* s_arr   = (float*)take((size_t)NN * HH * 4);
  float* d_arr   = (float*)take((size_t)NN * HH * 4);
  float* w_arr   = (float*)take((size_t)ET * HH * 4);
  int* deg       = (int*)take((size_t)NN * 4);
  int* cursor    = (int*)take((size_t)NN * 4);
  int* rowptr    = (int*)take((size_t)(NN + 1) * 4);
  int* eidlist   = (int*)take((size_t)ET * 4);
  float* colsum  = (float*)take(1024);
  float* colsumsq= (float*)take(1024);
  float* nscale  = (float*)take(1024);
  float* nshift  = (float*)take(1024);
  int* flag      = (int*)take(256);

  // CSR build (reused by all 3 layers)
  hipMemsetAsync(deg, 0, (size_t)NN * 4, stream);
  detect_kernel<<<1, 1, 0, stream>>>((const unsigned int*)ei, flag);
  degree_kernel<<<(ET + 255) / 256, 256, 0, stream>>>(ei, flag, deg);
  scan_kernel<<<1, 1024, 0, stream>>>(deg, rowptr, cursor);
  fill_kernel<<<(ET + 255) / 256, 256, 0, stream>>>(ei, flag, cursor, eidlist);

  const float* lin = x;
  for (int L = 0; L < 3; L++) {
    sgemm_kernel<<<dim3((NN + 127) / 128, 2), 256, 0, stream>>>(lin, W[L], bufA);
    sd_kernel<<<NN, 256, 0, stream>>>(bufA, as_[L], ad_[L], s_arr, d_arr);
    edgew_kernel<<<(ET + 255) / 256, 256, 0, stream>>>(ei, flag, s_arr, d_arr, w_arr);
    if (L < 2) {
      agg_kernel<true><<<NN, 256, 0, stream>>>(bufA, w_arr, rowptr, eidlist, ei, flag, b_[L], bufB);
      hipMemsetAsync(colsum, 0, 1024, stream);
      hipMemsetAsync(colsumsq, 0, 1024, stream);
      norm_reduce<<<(NN + 127) / 128, 256, 0, stream>>>(bufB, colsum, colsumsq, FDIM);
      norm_finalize<<<1, FDIM, 0, stream>>>(colsum, colsumsq, ga[L], gw[L], gb[L], nscale, nshift, FDIM);
      norm_apply<<<(NN * FDIM + 255) / 256, 256, 0, stream>>>(bufB, nscale, nshift, FDIM);
      lin = bufB;
    } else {
      agg_kernel<false><<<NN, 256, 0, stream>>>(bufA, w_arr, rowptr, eidlist, ei, flag, b_[L], bufD);
      hipMemsetAsync(colsum, 0, 1024, stream);
      hipMemsetAsync(colsumsq, 0, 1024, stream);
      norm_reduce<<<(NN + 127) / 128, 256, 0, stream>>>(bufD, colsum, colsumsq, CC);
      norm_finalize<<<1, CC, 0, stream>>>(colsum, colsumsq, ga[L], gw[L], gb[L], nscale, nshift, CC);
      norm_apply<<<(NN * CC + 255) / 256, 256, 0, stream>>>(bufD, nscale, nshift, CC);
    }
  }
  mlp_kernel<<<(NN + 255) / 256, 256, 0, stream>>>(bufD, mW0, mb0, mW1, mb1, mW2, mb2, out);
}

// Round 2
// 1298.658 us; speedup vs baseline: 1.4564x; 1.4564x over previous
//
#include <hip/hip_runtime.h>

#define NN 50000
#define EE 800000
#define ET 850000   // EE + NN self loops
#define HH 4
#define CC 64
#define FDIM 256    // HH*CC

typedef unsigned short ushort;
typedef __bf16 bf16x8 __attribute__((ext_vector_type(8)));
typedef float floatx4 __attribute__((ext_vector_type(4)));
typedef ushort ushort8v __attribute__((ext_vector_type(8)));
struct ushort4s { ushort x, y, z, w; };

__device__ __forceinline__ ushort f2bf(float f) {
  union { float f; unsigned u; } v; v.f = f;
  unsigned r = v.u + 0x7fffu + ((v.u >> 16) & 1u);  // RNE
  return (ushort)(r >> 16);
}
__device__ __forceinline__ float bf2f(ushort u) {
  return __uint_as_float(((unsigned)u) << 16);
}

// ---------- edge-index dtype handling (int32 vs int64 at runtime) ----------
__device__ __forceinline__ int get_edge(const void* p, int is64, long long idx) {
  if (is64) return (int)((const long long*)p)[idx];
  return ((const int*)p)[idx];
}

__global__ void detect_kernel(const unsigned int* p, int* flag) {
  unsigned int o = 0;
  for (int i = 1; i < 2048; i += 2) o |= p[i];
  *flag = (o == 0) ? 1 : 0;
}

// ---------- CSR build over dst ----------
__global__ void degree_kernel(const void* eidx, const int* flag, int* deg) {
  int k = blockIdx.x * blockDim.x + threadIdx.x;
  if (k >= ET) return;
  int is64 = *flag;
  int dst = (k < EE) ? get_edge(eidx, is64, (long long)EE + k) : (k - EE);
  atomicAdd(&deg[dst], 1);
}

__global__ __launch_bounds__(1024) void scan_kernel(const int* deg, int* rowptr, int* cursor) {
  __shared__ int partial[1024];
  int t = threadIdx.x;
  const int chunk = (NN + 1023) / 1024;
  int start = t * chunk;
  int end = min(start + chunk, NN);
  int sum = 0;
  for (int i = start; i < end; i++) sum += deg[i];
  partial[t] = sum;
  __syncthreads();
  for (int o = 1; o < 1024; o <<= 1) {
    int v = (t >= o) ? partial[t - o] : 0;
    __syncthreads();
    partial[t] += v;
    __syncthreads();
  }
  int run = (t == 0) ? 0 : partial[t - 1];
  for (int i = start; i < end; i++) {
    rowptr[i] = run; cursor[i] = run; run += deg[i];
  }
  if (t == 1023) rowptr[NN] = partial[1023];
}

__global__ void fill_kernel(const void* eidx, const int* flag, int* cursor, int* csr_src) {
  int k = blockIdx.x * blockDim.x + threadIdx.x;
  if (k >= ET) return;
  int is64 = *flag;
  int src, dst;
  if (k < EE) {
    src = get_edge(eidx, is64, k);
    dst = get_edge(eidx, is64, (long long)EE + k);
  } else {
    src = dst = k - EE;
  }
  int pos = atomicAdd(&cursor[dst], 1);
  csr_src[pos] = src;
}

// ---------- dtype conversions ----------
__global__ void conv_x_kernel(const float* __restrict__ x, ushort* __restrict__ xb) {
  int i = blockIdx.x * 256 + threadIdx.x;  // group of 4, NN*256/4 groups
  float4 v = ((const float4*)x)[i];
  ushort4s o;
  o.x = f2bf(v.x); o.y = f2bf(v.y); o.z = f2bf(v.z); o.w = f2bf(v.w);
  ((ushort4s*)xb)[i] = o;
}

__global__ void conv_w_kernel(const float* __restrict__ W, ushort* __restrict__ Wt) {
  int idx = blockIdx.x * 256 + threadIdx.x;  // 65536
  int k = idx >> 8, n = idx & 255;
  Wt[n * 256 + k] = f2bf(W[idx]);  // transpose: Wt[n][k]
}

// ---------- bf16 MFMA GEMM: C[M,256] = A[M,256] @ B[256,256], B given transposed ----------
// Tile 128x128, BK=32. LDS staged in MFMA-fragment order:
// A-subtile s (16 rows): lane l's 16B = A[row0+s*16+(l&15)][k0+(l>>4)*8 ..+7] at As[s*512 + l*8]
// => ds_read_b128 at lane*16 is the exact A-frag for mfma_f32_16x16x32_bf16 (m=l&15, k=(l>>4)*8+j)
__global__ __launch_bounds__(256) void gemm_bf16(const ushort* __restrict__ A,
                                                 const ushort* __restrict__ Bt,
                                                 ushort* __restrict__ C) {
  __shared__ ushort As[8 * 512];
  __shared__ ushort Bs[8 * 512];
  int tid = threadIdx.x, w = tid >> 6, l = tid & 63;
  int brow0 = blockIdx.x * 128, bcol0 = blockIdx.y * 128;
  int lm = l & 15, lk = (l >> 4) * 8;
  int s0 = 2 * w, s1 = 2 * w + 1;
  int ar0 = min(brow0 + s0 * 16 + lm, NN - 1);
  int ar1 = min(brow0 + s1 * 16 + lm, NN - 1);
  const ushort* ag0 = A + (size_t)ar0 * 256 + lk;
  const ushort* ag1 = A + (size_t)ar1 * 256 + lk;
  const ushort* bg0 = Bt + (size_t)(bcol0 + s0 * 16 + lm) * 256 + lk;
  const ushort* bg1 = Bt + (size_t)(bcol0 + s1 * 16 + lm) * 256 + lk;

  floatx4 acc[4][4];
#pragma unroll
  for (int i = 0; i < 4; i++)
#pragma unroll
    for (int j = 0; j < 4; j++) acc[i][j] = floatx4{0.f, 0.f, 0.f, 0.f};

  int wm = (w >> 1) * 4, wn = (w & 1) * 4;

  for (int k0 = 0; k0 < 256; k0 += 32) {
    ushort8v a0 = *(const ushort8v*)(ag0 + k0);
    ushort8v a1 = *(const ushort8v*)(ag1 + k0);
    ushort8v b0 = *(const ushort8v*)(bg0 + k0);
    ushort8v b1 = *(const ushort8v*)(bg1 + k0);
    *(ushort8v*)&As[s0 * 512 + l * 8] = a0;
    *(ushort8v*)&As[s1 * 512 + l * 8] = a1;
    *(ushort8v*)&Bs[s0 * 512 + l * 8] = b0;
    *(ushort8v*)&Bs[s1 * 512 + l * 8] = b1;
    __syncthreads();
    bf16x8 af[4], bfr[4];
#pragma unroll
    for (int i = 0; i < 4; i++) af[i] = *(const bf16x8*)&As[(wm + i) * 512 + l * 8];
#pragma unroll
    for (int j = 0; j < 4; j++) bfr[j] = *(const bf16x8*)&Bs[(wn + j) * 512 + l * 8];
#pragma unroll
    for (int i = 0; i < 4; i++)
#pragma unroll
      for (int j = 0; j < 4; j++)
        acc[i][j] = __builtin_amdgcn_mfma_f32_16x16x32_bf16(af[i], bfr[j], acc[i][j], 0, 0, 0);
    __syncthreads();
  }

  int quad = l >> 4;
#pragma unroll
  for (int i = 0; i < 4; i++) {
    int r0 = brow0 + (wm + i) * 16 + quad * 4;
#pragma unroll
    for (int j = 0; j < 4; j++) {
      int col = bcol0 + (wn + j) * 16 + lm;
#pragma unroll
      for (int r = 0; r < 4; r++) {
        int row = r0 + r;
        if (row < NN) C[(size_t)row * 256 + col] = f2bf(acc[i][j][r]);
      }
    }
  }
}

// ---------- attention logits s,d per (node, head), bf16 h ----------
__global__ __launch_bounds__(256) void sd_kernel(const ushort* __restrict__ h,
                                                 const float* __restrict__ as_,
                                                 const float* __restrict__ ad_,
                                                 float* __restrict__ s, float* __restrict__ d) {
  int n = blockIdx.x;
  int wv = threadIdx.x >> 6;
  int lane = threadIdx.x & 63;
  float v = bf2f(h[(size_t)n * FDIM + wv * CC + lane]);
  float ps = v * as_[wv * CC + lane];
  float pd = v * ad_[wv * CC + lane];
#pragma unroll
  for (int o = 32; o > 0; o >>= 1) {
    ps += __shfl_xor(ps, o);
    pd += __shfl_xor(pd, o);
  }
  if (lane == 0) { s[n * HH + wv] = ps; d[n * HH + wv] = pd; }
}

// ---------- aggregation with fused edge softmax weights ----------
// one block per dst node, one wave per head, lane = channel; bf16 gather of h[src]
template <bool CONCAT>
__global__ __launch_bounds__(256) void agg_kernel(const ushort* __restrict__ hb,
                                                  const float* __restrict__ s_arr,
                                                  const float* __restrict__ d_arr,
                                                  const int* __restrict__ rowptr,
                                                  const int* __restrict__ csr_src,
                                                  const float* __restrict__ bias,
                                                  void* __restrict__ outp) {
  __shared__ float tmp[256];
  int n = blockIdx.x;
  int wv = threadIdx.x >> 6;
  int lane = threadIdx.x & 63;
  int beg = rowptr[n], end = rowptr[n + 1];
  float dn = d_arr[n * HH + wv];
  float acc = 0.f, den = 0.f;
  for (int i = beg; i < end; i++) {
    int src = csr_src[i];
    float e = s_arr[src * HH + wv] + dn;
    e = (e > 0.f) ? e : 0.2f * e;     // LeakyReLU(0.2) attention slope
    float wt = __expf(e);             // softmax shift-invariant: no max pass needed
    den += wt;
    float hv = bf2f(hb[(size_t)src * FDIM + wv * CC + lane]);
    acc = fmaf(wt, hv, acc);
  }
  float res = acc / den;  // self loop guarantees den > 0
  if (CONCAT) {
    ((ushort*)outp)[(size_t)n * FDIM + threadIdx.x] = f2bf(res + bias[threadIdx.x]);
  } else {
    tmp[threadIdx.x] = res;
    __syncthreads();
    if (threadIdx.x < 64) {
      float m = 0.25f * (tmp[lane] + tmp[64 + lane] + tmp[128 + lane] + tmp[192 + lane]);
      ((float*)outp)[(size_t)n * CC + lane] = m + bias[lane];
    }
  }
}

// ---------- GraphNorm ----------
__global__ __launch_bounds__(256) void norm_reduce_bf(const ushort* __restrict__ xin,
                                                      float* colsum, float* colsumsq) {
  int f = threadIdx.x;
  int r0 = blockIdx.x * 128;
  int r1 = min(NN, r0 + 128);
  float s1 = 0.f, s2 = 0.f;
  for (int r = r0; r < r1; r++) {
    float v = bf2f(xin[(size_t)r * FDIM + f]);
    s1 += v; s2 += v * v;
  }
  atomicAdd(&colsum[f], s1);
  atomicAdd(&colsumsq[f], s2);
}

__global__ __launch_bounds__(256) void norm_reduce_f32(const float* __restrict__ xin,
                                                       float* colsum, float* colsumsq, int F) {
  int f = threadIdx.x & (F - 1);
  int rl = threadIdx.x / F;
  int rpb = 256 / F;
  int r0 = blockIdx.x * 128;
  int r1 = min(NN, r0 + 128);
  float s1 = 0.f, s2 = 0.f;
  for (int r = r0 + rl; r < r1; r += rpb) {
    float v = xin[(size_t)r * F + f];
    s1 += v; s2 += v * v;
  }
  atomicAdd(&colsum[f], s1);
  atomicAdd(&colsumsq[f], s2);
}

__global__ void norm_finalize(const float* colsum, const float* colsumsq,
                              const float* ga, const float* gw, const float* gb,
                              float* nscale, float* nshift, int F) {
  int f = threadIdx.x;
  if (f >= F) return;
  const float invn = 1.0f / (float)NN;
  float mu = colsum[f] * invn;
  float ex2 = colsumsq[f] * invn;
  float a = ga[f];
  float var = ex2 - (2.f * a - a * a) * mu * mu;  // E[(x-a*mu)^2]
  var = fmaxf(var, 0.f);
  float sc = gw[f] * rsqrtf(var + 1e-5f);
  nscale[f] = sc;
  nshift[f] = gb[f] - sc * a * mu;
}

// bf16 in -> scale/shift -> LeakyReLU(0.01) -> bf16 out (next layer's GEMM input)
__global__ void norm_apply_bf(const ushort* __restrict__ in, ushort* __restrict__ outb,
                              const float* __restrict__ nscale, const float* __restrict__ nshift) {
  int i = blockIdx.x * 256 + threadIdx.x;  // group of 4; NN*256/4 groups
  int f0 = (i * 4) & (FDIM - 1);
  ushort4s v = ((const ushort4s*)in)[i];
  float y0 = nscale[f0 + 0] * bf2f(v.x) + nshift[f0 + 0];
  float y1 = nscale[f0 + 1] * bf2f(v.y) + nshift[f0 + 1];
  float y2 = nscale[f0 + 2] * bf2f(v.z) + nshift[f0 + 2];
  float y3 = nscale[f0 + 3] * bf2f(v.w) + nshift[f0 + 3];
  ushort4s o;
  o.x = f2bf((y0 > 0.f) ? y0 : 0.01f * y0);
  o.y = f2bf((y1 > 0.f) ? y1 : 0.01f * y1);
  o.z = f2bf((y2 > 0.f) ? y2 : 0.01f * y2);
  o.w = f2bf((y3 > 0.f) ? y3 : 0.01f * y3);
  ((ushort4s*)outb)[i] = o;
}

__global__ void norm_apply_f32(float* xio, const float* __restrict__ nscale,
                               const float* __restrict__ nshift, int F) {
  long long i = (long long)blockIdx.x * 256 + threadIdx.x;
  if (i >= (long long)NN * F) return;
  int f = (int)(i & (F - 1));
  float y = nscale[f] * xio[i] + nshift[f];
  xio[i] = (y > 0.f) ? y : 0.01f * y;
}

// ---------- MLP 64->32->16->2, weights in LDS, one thread per node ----------
__global__ __launch_bounds__(256) void mlp_kernel(const float* __restrict__ xin,
                                                  const float* mW0, const float* mb0,
                                                  const float* mW1, const float* mb1,
                                                  const float* mW2, const float* mb2,
                                                  float* __restrict__ out) {
  __shared__ float W0s[64 * 32];
  __shared__ float W1s[32 * 16];
  __shared__ float W2s[16 * 2];
  __shared__ float b0s[32], b1s[16], b2s[2];
  int t = threadIdx.x;
  for (int i = t; i < 2048; i += 256) W0s[i] = mW0[i];
  for (int i = t; i < 512; i += 256) W1s[i] = mW1[i];
  if (t < 32) { W2s[t] = mW2[t]; b0s[t] = mb0[t]; }
  if (t < 16) b1s[t] = mb1[t];
  if (t < 2) b2s[t] = mb2[t];
  __syncthreads();
  int node = blockIdx.x * 256 + t;
  if (node >= NN) return;
  float in[64];
  const float* xr = xin + (size_t)node * 64;
#pragma unroll
  for (int k = 0; k < 64; k++) in[k] = xr[k];
  float h1[32];
#pragma unroll
  for (int j = 0; j < 32; j++) h1[j] = b0s[j];
#pragma unroll
  for (int k = 0; k < 64; k++) {
    float v = in[k];
#pragma unroll
    for (int j = 0; j < 32; j++) h1[j] += v * W0s[k * 32 + j];
  }
#pragma unroll
  for (int j = 0; j < 32; j++) h1[j] = fmaxf(h1[j], 0.f);
  float h2[16];
#pragma unroll
  for (int j = 0; j < 16; j++) h2[j] = b1s[j];
#pragma unroll
  for (int k = 0; k < 32; k++) {
    float v = h1[k];
#pragma unroll
    for (int j = 0; j < 16; j++) h2[j] += v * W1s[k * 16 + j];
  }
#pragma unroll
  for (int j = 0; j < 16; j++) h2[j] = fmaxf(h2[j], 0.f);
  float o0 = b2s[0], o1 = b2s[1];
#pragma unroll
  for (int k = 0; k < 16; k++) {
    o0 += h2[k] * W2s[k * 2 + 0];
    o1 += h2[k] * W2s[k * 2 + 1];
  }
  out[(size_t)node * 2 + 0] = o0;
  out[(size_t)node * 2 + 1] = o1;
}

extern "C" void kernel_launch(void* const* d_in, const int* in_sizes, int n_in,
                              void* d_out, int out_size, void* d_ws, size_t ws_size,
                              hipStream_t stream) {
  const float* x = (const float*)d_in[0];
  const void* ei = d_in[1];
  const float* W[3]   = {(const float*)d_in[2],  (const float*)d_in[9],  (const float*)d_in[16]};
  const float* as_[3] = {(const float*)d_in[3],  (const float*)d_in[10], (const float*)d_in[17]};
  const float* ad_[3] = {(const float*)d_in[4],  (const float*)d_in[11], (const float*)d_in[18]};
  const float* b_[3]  = {(const float*)d_in[5],  (const float*)d_in[12], (const float*)d_in[19]};
  const float* gw[3]  = {(const float*)d_in[6],  (const float*)d_in[13], (const float*)d_in[20]};
  const float* gb[3]  = {(const float*)d_in[7],  (const float*)d_in[14], (const float*)d_in[21]};
  const float* ga[3]  = {(const float*)d_in[8],  (const float*)d_in[15], (const float*)d_in[22]};
  const float* mW0 = (const float*)d_in[23];
  const float* mb0 = (const float*)d_in[24];
  const float* mW1 = (const float*)d_in[25];
  const float* mb1 = (const float*)d_in[26];
  const float* mW2 = (const float*)d_in[27];
  const float* mb2 = (const float*)d_in[28];
  float* out = (float*)d_out;

  char* ws = (char*)d_ws;
  size_t off = 0;
  auto take = [&](size_t bytes) -> char* {
    char* p = ws + off;
    off = (off + bytes + 255) & ~(size_t)255;
    return p;
  };
  ushort* xb    = (ushort*)take((size_t)NN * FDIM * 2);
  ushort* hb    = (ushort*)take((size_t)NN * FDIM * 2);
  ushort* yb    = (ushort*)take((size_t)NN * FDIM * 2);
  ushort* aggb  = (ushort*)take((size_t)NN * FDIM * 2);
  float* bufD   = (float*)take((size_t)NN * CC * 4);
  ushort* Wt[3];
  for (int i = 0; i < 3; i++) Wt[i] = (ushort*)take((size_t)256 * 256 * 2);
  float* s_arr  = (float*)take((size_t)NN * HH * 4);
  float* d_arr  = (float*)take((size_t)NN * HH * 4);
  int* deg      = (int*)take((size_t)NN * 4);
  int* cursor   = (int*)take((size_t)NN * 4);
  int* rowptr   = (int*)take((size_t)(NN + 1) * 4);
  int* csr_src  = (int*)take((size_t)ET * 4);
  float* colsum   = (float*)take(1024);
  float* colsumsq = (float*)take(1024);
  float* nscale   = (float*)take(1024);
  float* nshift   = (float*)take(1024);
  int* flag       = (int*)take(256);

  // CSR build (reused by all 3 layers)
  hipMemsetAsync(deg, 0, (size_t)NN * 4, stream);
  detect_kernel<<<1, 1, 0, stream>>>((const unsigned int*)ei, flag);
  degree_kernel<<<(ET + 255) / 256, 256, 0, stream>>>(ei, flag, deg);
  scan_kernel<<<1, 1024, 0, stream>>>(deg, rowptr, cursor);
  fill_kernel<<<(ET + 255) / 256, 256, 0, stream>>>(ei, flag, cursor, csr_src);

  // dtype prep
  conv_x_kernel<<<(NN * FDIM / 4 + 255) / 256, 256, 0, stream>>>(x, xb);
  for (int L = 0; L < 3; L++)
    conv_w_kernel<<<256, 256, 0, stream>>>(W[L], Wt[L]);

  const ushort* lin = xb;
  for (int L = 0; L < 3; L++) {
    gemm_bf16<<<dim3((NN + 127) / 128, 2), 256, 0, stream>>>(lin, Wt[L], hb);
    sd_kernel<<<NN, 256, 0, stream>>>(hb, as_[L], ad_[L], s_arr, d_arr);
    hipMemsetAsync(colsum, 0, 1024, stream);
    hipMemsetAsync(colsumsq, 0, 1024, stream);
    if (L < 2) {
      agg_kernel<true><<<NN, 256, 0, stream>>>(hb, s_arr, d_arr, rowptr, csr_src, b_[L], aggb);
      norm_reduce_bf<<<(NN + 127) / 128, 256, 0, stream>>>(aggb, colsum, colsumsq);
      norm_finalize<<<1, FDIM, 0, stream>>>(colsum, colsumsq, ga[L], gw[L], gb[L], nscale, nshift, FDIM);
      norm_apply_bf<<<(NN * FDIM / 4 + 255) / 256, 256, 0, stream>>>(aggb, yb, nscale, nshift);
      lin = yb;
    } else {
      agg_kernel<false><<<NN, 256, 0, stream>>>(hb, s_arr, d_arr, rowptr, csr_src, b_[L], bufD);
      norm_reduce_f32<<<(NN + 127) / 128, 256, 0, stream>>>(bufD, colsum, colsumsq, CC);
      norm_finalize<<<1, CC, 0, stream>>>(colsum, colsumsq, ga[L], gw[L], gb[L], nscale, nshift, CC);
      norm_apply_f32<<<(NN * CC + 255) / 256, 256, 0, stream>>>(bufD, nscale, nshift, CC);
    }
  }
  mlp_kernel<<<(NN + 255) / 256, 256, 0, stream>>>(bufD, mW0, mb0, mW1, mb1, mW2, mb2, out);
}

// Round 3
// 1036.623 us; speedup vs baseline: 1.8245x; 1.2528x over previous
//
#include <hip/hip_runtime.h>

#define NN 50000
#define EE 800000
#define ET 850000   // EE + NN self loops
#define HH 4
#define CC 64
#define FDIM 256    // HH*CC

typedef unsigned short ushort;
typedef __bf16 bf16x8 __attribute__((ext_vector_type(8)));
typedef float floatx4 __attribute__((ext_vector_type(4)));
typedef ushort ushort8v __attribute__((ext_vector_type(8)));
struct ushort4s { ushort x, y, z, w; };

__device__ __forceinline__ ushort f2bf(float f) {
  union { float f; unsigned u; } v; v.f = f;
  unsigned r = v.u + 0x7fffu + ((v.u >> 16) & 1u);  // RNE
  return (ushort)(r >> 16);
}
__device__ __forceinline__ float bf2f(ushort u) {
  return __uint_as_float(((unsigned)u) << 16);
}

// ---------- edge-index dtype handling (int32 vs int64 at runtime) ----------
__device__ __forceinline__ int get_edge(const void* p, int is64, long long idx) {
  if (is64) return (int)((const long long*)p)[idx];
  return ((const int*)p)[idx];
}

__global__ void detect_kernel(const unsigned int* p, int* flag) {
  // int64 with values < 50000 => every odd 32-bit word is 0
  __shared__ unsigned red[256];
  int t = threadIdx.x;
  unsigned o = 0;
  for (int i = 0; i < 4; i++) o |= p[(t * 4 + i) * 2 + 1];
  red[t] = o;
  __syncthreads();
  for (int s = 128; s > 0; s >>= 1) {
    if (t < s) red[t] |= red[t + s];
    __syncthreads();
  }
  if (t == 0) *flag = (red[0] == 0) ? 1 : 0;
}

// ---------- CSR build over dst ----------
__global__ void degree_kernel(const void* eidx, const int* flag, int* deg) {
  int k = blockIdx.x * blockDim.x + threadIdx.x;
  if (k >= ET) return;
  int is64 = *flag;
  int dst = (k < EE) ? get_edge(eidx, is64, (long long)EE + k) : (k - EE);
  atomicAdd(&deg[dst], 1);
}

__global__ __launch_bounds__(1024) void scan_kernel(const int* deg, int* rowptr, int* cursor) {
  __shared__ int partial[1024];
  int t = threadIdx.x;
  const int chunk = (NN + 1023) / 1024;
  int start = t * chunk;
  int end = min(start + chunk, NN);
  int sum = 0;
  for (int i = start; i < end; i++) sum += deg[i];
  partial[t] = sum;
  __syncthreads();
  for (int o = 1; o < 1024; o <<= 1) {
    int v = (t >= o) ? partial[t - o] : 0;
    __syncthreads();
    partial[t] += v;
    __syncthreads();
  }
  int run = (t == 0) ? 0 : partial[t - 1];
  for (int i = start; i < end; i++) {
    rowptr[i] = run; cursor[i] = run; run += deg[i];
  }
  if (t == 1023) rowptr[NN] = partial[1023];
}

__global__ void fill_kernel(const void* eidx, const int* flag, int* cursor,
                            int* csr_src, int* csr_dst) {
  int k = blockIdx.x * blockDim.x + threadIdx.x;
  if (k >= ET) return;
  int is64 = *flag;
  int src, dst;
  if (k < EE) {
    src = get_edge(eidx, is64, k);
    dst = get_edge(eidx, is64, (long long)EE + k);
  } else {
    src = dst = k - EE;
  }
  int pos = atomicAdd(&cursor[dst], 1);
  csr_src[pos] = src;
  csr_dst[pos] = dst;
}

// ---------- dtype conversions ----------
__global__ void conv_x_kernel(const float* __restrict__ x, ushort* __restrict__ xb) {
  int i = blockIdx.x * 256 + threadIdx.x;
  float4 v = ((const float4*)x)[i];
  ushort4s o;
  o.x = f2bf(v.x); o.y = f2bf(v.y); o.z = f2bf(v.z); o.w = f2bf(v.w);
  ((ushort4s*)xb)[i] = o;
}

__global__ void conv_w_kernel(const float* __restrict__ W, ushort* __restrict__ Wt) {
  int idx = blockIdx.x * 256 + threadIdx.x;  // 65536
  int k = idx >> 8, n = idx & 255;
  Wt[n * 256 + k] = f2bf(W[idx]);  // transpose: Wt[n][k]
}

// ---------- bf16 MFMA GEMM: C[M,256] = A[M,256] @ B[256,256], B given transposed ----------
__global__ __launch_bounds__(256) void gemm_bf16(const ushort* __restrict__ A,
                                                 const ushort* __restrict__ Bt,
                                                 ushort* __restrict__ C) {
  __shared__ ushort As[8 * 512];
  __shared__ ushort Bs[8 * 512];
  int tid = threadIdx.x, w = tid >> 6, l = tid & 63;
  int brow0 = blockIdx.x * 128, bcol0 = blockIdx.y * 128;
  int lm = l & 15, lk = (l >> 4) * 8;
  int s0 = 2 * w, s1 = 2 * w + 1;
  int ar0 = min(brow0 + s0 * 16 + lm, NN - 1);
  int ar1 = min(brow0 + s1 * 16 + lm, NN - 1);
  const ushort* ag0 = A + (size_t)ar0 * 256 + lk;
  const ushort* ag1 = A + (size_t)ar1 * 256 + lk;
  const ushort* bg0 = Bt + (size_t)(bcol0 + s0 * 16 + lm) * 256 + lk;
  const ushort* bg1 = Bt + (size_t)(bcol0 + s1 * 16 + lm) * 256 + lk;

  floatx4 acc[4][4];
#pragma unroll
  for (int i = 0; i < 4; i++)
#pragma unroll
    for (int j = 0; j < 4; j++) acc[i][j] = floatx4{0.f, 0.f, 0.f, 0.f};

  int wm = (w >> 1) * 4, wn = (w & 1) * 4;

  for (int k0 = 0; k0 < 256; k0 += 32) {
    ushort8v a0 = *(const ushort8v*)(ag0 + k0);
    ushort8v a1 = *(const ushort8v*)(ag1 + k0);
    ushort8v b0 = *(const ushort8v*)(bg0 + k0);
    ushort8v b1 = *(const ushort8v*)(bg1 + k0);
    *(ushort8v*)&As[s0 * 512 + l * 8] = a0;
    *(ushort8v*)&As[s1 * 512 + l * 8] = a1;
    *(ushort8v*)&Bs[s0 * 512 + l * 8] = b0;
    *(ushort8v*)&Bs[s1 * 512 + l * 8] = b1;
    __syncthreads();
    bf16x8 af[4], bfr[4];
#pragma unroll
    for (int i = 0; i < 4; i++) af[i] = *(const bf16x8*)&As[(wm + i) * 512 + l * 8];
#pragma unroll
    for (int j = 0; j < 4; j++) bfr[j] = *(const bf16x8*)&Bs[(wn + j) * 512 + l * 8];
#pragma unroll
    for (int i = 0; i < 4; i++)
#pragma unroll
      for (int j = 0; j < 4; j++)
        acc[i][j] = __builtin_amdgcn_mfma_f32_16x16x32_bf16(af[i], bfr[j], acc[i][j], 0, 0, 0);
    __syncthreads();
  }

  int quad = l >> 4;
#pragma unroll
  for (int i = 0; i < 4; i++) {
    int r0 = brow0 + (wm + i) * 16 + quad * 4;
#pragma unroll
    for (int j = 0; j < 4; j++) {
      int col = bcol0 + (wn + j) * 16 + lm;
#pragma unroll
      for (int r = 0; r < 4; r++) {
        int row = r0 + r;
        if (row < NN) C[(size_t)row * 256 + col] = f2bf(acc[i][j][r]);
      }
    }
  }
}

// ---------- attention logits s,d per (node, head), bf16 h ----------
__global__ __launch_bounds__(256) void sd_kernel(const ushort* __restrict__ h,
                                                 const float* __restrict__ as_,
                                                 const float* __restrict__ ad_,
                                                 float* __restrict__ s, float* __restrict__ d) {
  int n = blockIdx.x;
  int wv = threadIdx.x >> 6;
  int lane = threadIdx.x & 63;
  float v = bf2f(h[(size_t)n * FDIM + wv * CC + lane]);
  float ps = v * as_[wv * CC + lane];
  float pd = v * ad_[wv * CC + lane];
#pragma unroll
  for (int o = 32; o > 0; o >>= 1) {
    ps += __shfl_xor(ps, o);
    pd += __shfl_xor(pd, o);
  }
  if (lane == 0) { s[n * HH + wv] = ps; d[n * HH + wv] = pd; }
}

// ---------- edge weights in CSR order: wt[e][h] = exp(leakyrelu(s[src][h]+d[dst][h], 0.2)) ----------
__global__ void edgew_kernel(const int* __restrict__ csr_src, const int* __restrict__ csr_dst,
                             const float* __restrict__ s_arr, const float* __restrict__ d_arr,
                             float* __restrict__ wt) {
  int k = blockIdx.x * 256 + threadIdx.x;
  if (k >= ET) return;
  int src = csr_src[k], dst = csr_dst[k];
  float4 ss = ((const float4*)s_arr)[src];
  float4 dd = ((const float4*)d_arr)[dst];
  float4 r;
  float t;
  t = ss.x + dd.x; t = (t > 0.f) ? t : 0.2f * t; r.x = __expf(t);
  t = ss.y + dd.y; t = (t > 0.f) ? t : 0.2f * t; r.y = __expf(t);
  t = ss.z + dd.z; t = (t > 0.f) ? t : 0.2f * t; r.z = __expf(t);
  t = ss.w + dd.w; t = (t > 0.f) ? t : 0.2f * t; r.w = __expf(t);
  ((float4*)wt)[k] = r;
}

// ---------- aggregation: one block per dst node, one wave per head, lane = channel ----------
// src/wt at wave-uniform addresses -> scalar loads; single bf16 gather per edge.
template <bool CONCAT>
__global__ __launch_bounds__(256) void agg_kernel(const ushort* __restrict__ hb,
                                                  const float* __restrict__ wt,
                                                  const int* __restrict__ rowptr,
                                                  const int* __restrict__ csr_src,
                                                  const float* __restrict__ bias,
                                                  void* __restrict__ outp) {
  __shared__ float tmp[256];
  int n = blockIdx.x;
  int wv = __builtin_amdgcn_readfirstlane(threadIdx.x >> 6);
  int lane = threadIdx.x & 63;
  int beg = rowptr[n], end = rowptr[n + 1];
  int lofs = wv * CC + lane;
  float acc = 0.f, den = 0.f;
  int i = beg;
  for (; i + 4 <= end; i += 4) {
    int s0 = csr_src[i], s1 = csr_src[i + 1], s2 = csr_src[i + 2], s3 = csr_src[i + 3];
    float w0 = wt[i * 4 + wv], w1 = wt[(i + 1) * 4 + wv];
    float w2 = wt[(i + 2) * 4 + wv], w3 = wt[(i + 3) * 4 + wv];
    float h0 = bf2f(hb[(unsigned)(s0 * FDIM + lofs)]);
    float h1 = bf2f(hb[(unsigned)(s1 * FDIM + lofs)]);
    float h2 = bf2f(hb[(unsigned)(s2 * FDIM + lofs)]);
    float h3 = bf2f(hb[(unsigned)(s3 * FDIM + lofs)]);
    den += (w0 + w1) + (w2 + w3);
    acc = fmaf(w0, h0, acc);
    acc = fmaf(w1, h1, acc);
    acc = fmaf(w2, h2, acc);
    acc = fmaf(w3, h3, acc);
  }
  for (; i < end; i++) {
    int s0 = csr_src[i];
    float w0 = wt[i * 4 + wv];
    float h0 = bf2f(hb[(unsigned)(s0 * FDIM + lofs)]);
    den += w0;
    acc = fmaf(w0, h0, acc);
  }
  float res = acc / den;  // self loop guarantees den > 0
  if (CONCAT) {
    ((ushort*)outp)[(size_t)n * FDIM + threadIdx.x] = f2bf(res + bias[threadIdx.x]);
  } else {
    tmp[threadIdx.x] = res;
    __syncthreads();
    if (threadIdx.x < 64) {
      float m = 0.25f * (tmp[lane] + tmp[64 + lane] + tmp[128 + lane] + tmp[192 + lane]);
      ((float*)outp)[(size_t)n * CC + lane] = m + bias[lane];
    }
  }
}

// ---------- GraphNorm ----------
__global__ __launch_bounds__(256) void norm_reduce_bf(const ushort* __restrict__ xin,
                                                      float* colsum, float* colsumsq) {
  int f = threadIdx.x;
  int r0 = blockIdx.x * 128;
  int r1 = min(NN, r0 + 128);
  float s1 = 0.f, s2 = 0.f;
  for (int r = r0; r < r1; r++) {
    float v = bf2f(xin[(size_t)r * FDIM + f]);
    s1 += v; s2 += v * v;
  }
  atomicAdd(&colsum[f], s1);
  atomicAdd(&colsumsq[f], s2);
}

__global__ __launch_bounds__(256) void norm_reduce_f32(const float* __restrict__ xin,
                                                       float* colsum, float* colsumsq) {
  int f = threadIdx.x & (CC - 1);
  int rl = threadIdx.x / CC;
  int r0 = blockIdx.x * 128;
  int r1 = min(NN, r0 + 128);
  float s1 = 0.f, s2 = 0.f;
  for (int r = r0 + rl; r < r1; r += 4) {
    float v = xin[(size_t)r * CC + f];
    s1 += v; s2 += v * v;
  }
  atomicAdd(&colsum[f], s1);
  atomicAdd(&colsumsq[f], s2);
}

// finalize folded in: each block recomputes scale/shift (cheap), then grid-stride apply
__global__ __launch_bounds__(256) void norm_apply_bf(const ushort* __restrict__ in,
                                                     ushort* __restrict__ outb,
                                                     const float* __restrict__ colsum,
                                                     const float* __restrict__ colsumsq,
                                                     const float* __restrict__ ga,
                                                     const float* __restrict__ gw,
                                                     const float* __restrict__ gb) {
  __shared__ float sc[FDIM], sh[FDIM];
  int t = threadIdx.x;
  {
    const float invn = 1.0f / (float)NN;
    float mu = colsum[t] * invn;
    float ex2 = colsumsq[t] * invn;
    float a = ga[t];
    float var = fmaxf(ex2 - (2.f * a - a * a) * mu * mu, 0.f);
    float s = gw[t] * rsqrtf(var + 1e-5f);
    sc[t] = s; sh[t] = gb[t] - s * a * mu;
  }
  __syncthreads();
  const int total = NN * FDIM / 4;
  for (int i = blockIdx.x * 256 + t; i < total; i += gridDim.x * 256) {
    int f0 = (i * 4) & (FDIM - 1);
    ushort4s v = ((const ushort4s*)in)[i];
    float y0 = sc[f0 + 0] * bf2f(v.x) + sh[f0 + 0];
    float y1 = sc[f0 + 1] * bf2f(v.y) + sh[f0 + 1];
    float y2 = sc[f0 + 2] * bf2f(v.z) + sh[f0 + 2];
    float y3 = sc[f0 + 3] * bf2f(v.w) + sh[f0 + 3];
    ushort4s o;
    o.x = f2bf((y0 > 0.f) ? y0 : 0.01f * y0);
    o.y = f2bf((y1 > 0.f) ? y1 : 0.01f * y1);
    o.z = f2bf((y2 > 0.f) ? y2 : 0.01f * y2);
    o.w = f2bf((y3 > 0.f) ? y3 : 0.01f * y3);
    ((ushort4s*)outb)[i] = o;
  }
}

__global__ __launch_bounds__(256) void norm_apply_f32(float* __restrict__ xio,
                                                      const float* __restrict__ colsum,
                                                      const float* __restrict__ colsumsq,
                                                      const float* __restrict__ ga,
                                                      const float* __restrict__ gw,
                                                      const float* __restrict__ gb) {
  __shared__ float sc[CC], sh[CC];
  int t = threadIdx.x;
  if (t < CC) {
    const float invn = 1.0f / (float)NN;
    float mu = colsum[t] * invn;
    float ex2 = colsumsq[t] * invn;
    float a = ga[t];
    float var = fmaxf(ex2 - (2.f * a - a * a) * mu * mu, 0.f);
    float s = gw[t] * rsqrtf(var + 1e-5f);
    sc[t] = s; sh[t] = gb[t] - s * a * mu;
  }
  __syncthreads();
  const int total = NN * CC;
  for (int i = blockIdx.x * 256 + t; i < total; i += gridDim.x * 256) {
    int f = i & (CC - 1);
    float y = sc[f] * xio[i] + sh[f];
    xio[i] = (y > 0.f) ? y : 0.01f * y;
  }
}

// ---------- MLP 64->32->16->2, weights in LDS, one thread per node ----------
__global__ __launch_bounds__(256) void mlp_kernel(const float* __restrict__ xin,
                                                  const float* mW0, const float* mb0,
                                                  const float* mW1, const float* mb1,
                                                  const float* mW2, const float* mb2,
                                                  float* __restrict__ out) {
  __shared__ float W0s[64 * 32];
  __shared__ float W1s[32 * 16];
  __shared__ float W2s[16 * 2];
  __shared__ float b0s[32], b1s[16], b2s[2];
  int t = threadIdx.x;
  for (int i = t; i < 2048; i += 256) W0s[i] = mW0[i];
  for (int i = t; i < 512; i += 256) W1s[i] = mW1[i];
  if (t < 32) { W2s[t] = mW2[t]; b0s[t] = mb0[t]; }
  if (t < 16) b1s[t] = mb1[t];
  if (t < 2) b2s[t] = mb2[t];
  __syncthreads();
  int node = blockIdx.x * 256 + t;
  if (node >= NN) return;
  float in[64];
  const float* xr = xin + (size_t)node * 64;
#pragma unroll
  for (int k = 0; k < 64; k++) in[k] = xr[k];
  float h1[32];
#pragma unroll
  for (int j = 0; j < 32; j++) h1[j] = b0s[j];
#pragma unroll
  for (int k = 0; k < 64; k++) {
    float v = in[k];
#pragma unroll
    for (int j = 0; j < 32; j++) h1[j] += v * W0s[k * 32 + j];
  }
#pragma unroll
  for (int j = 0; j < 32; j++) h1[j] = fmaxf(h1[j], 0.f);
  float h2[16];
#pragma unroll
  for (int j = 0; j < 16; j++) h2[j] = b1s[j];
#pragma unroll
  for (int k = 0; k < 32; k++) {
    float v = h1[k];
#pragma unroll
    for (int j = 0; j < 16; j++) h2[j] += v * W1s[k * 16 + j];
  }
#pragma unroll
  for (int j = 0; j < 16; j++) h2[j] = fmaxf(h2[j], 0.f);
  float o0 = b2s[0], o1 = b2s[1];
#pragma unroll
  for (int k = 0; k < 16; k++) {
    o0 += h2[k] * W2s[k * 2 + 0];
    o1 += h2[k] * W2s[k * 2 + 1];
  }
  out[(size_t)node * 2 + 0] = o0;
  out[(size_t)node * 2 + 1] = o1;
}

extern "C" void kernel_launch(void* const* d_in, const int* in_sizes, int n_in,
                              void* d_out, int out_size, void* d_ws, size_t ws_size,
                              hipStream_t stream) {
  const float* x = (const float*)d_in[0];
  const void* ei = d_in[1];
  const float* W[3]   = {(const float*)d_in[2],  (const float*)d_in[9],  (const float*)d_in[16]};
  const float* as_[3] = {(const float*)d_in[3],  (const float*)d_in[10], (const float*)d_in[17]};
  const float* ad_[3] = {(const float*)d_in[4],  (const float*)d_in[11], (const float*)d_in[18]};
  const float* b_[3]  = {(const float*)d_in[5],  (const float*)d_in[12], (const float*)d_in[19]};
  const float* gw[3]  = {(const float*)d_in[6],  (const float*)d_in[13], (const float*)d_in[20]};
  const float* gb[3]  = {(const float*)d_in[7],  (const float*)d_in[14], (const float*)d_in[21]};
  const float* ga[3]  = {(const float*)d_in[8],  (const float*)d_in[15], (const float*)d_in[22]};
  const float* mW0 = (const float*)d_in[23];
  const float* mb0 = (const float*)d_in[24];
  const float* mW1 = (const float*)d_in[25];
  const float* mb1 = (const float*)d_in[26];
  const float* mW2 = (const float*)d_in[27];
  const float* mb2 = (const float*)d_in[28];
  float* out = (float*)d_out;

  char* ws = (char*)d_ws;
  size_t off = 0;
  auto take = [&](size_t bytes) -> char* {
    char* p = ws + off;
    off = (off + bytes + 255) & ~(size_t)255;
    return p;
  };
  ushort* xb    = (ushort*)take((size_t)NN * FDIM * 2);
  ushort* hb    = (ushort*)take((size_t)NN * FDIM * 2);
  ushort* yb    = (ushort*)take((size_t)NN * FDIM * 2);
  ushort* aggb  = (ushort*)take((size_t)NN * FDIM * 2);
  float* bufD   = (float*)take((size_t)NN * CC * 4);
  ushort* Wt[3];
  for (int i = 0; i < 3; i++) Wt[i] = (ushort*)take((size_t)256 * 256 * 2);
  float* s_arr  = (float*)take((size_t)NN * HH * 4);
  float* d_arr  = (float*)take((size_t)NN * HH * 4);
  float* wt_arr = (float*)take((size_t)ET * HH * 4);
  int* deg      = (int*)take((size_t)NN * 4);
  int* cursor   = (int*)take((size_t)NN * 4);
  int* rowptr   = (int*)take((size_t)(NN + 1) * 4);
  int* csr_src  = (int*)take((size_t)ET * 4);
  int* csr_dst  = (int*)take((size_t)ET * 4);
  float* colsum   = (float*)take(1024);   // colsum+colsumsq contiguous: one memset
  float* colsumsq = (float*)take(1024);
  int* flag       = (int*)take(256);

  // CSR build (reused by all 3 layers)
  hipMemsetAsync(deg, 0, (size_t)NN * 4, stream);
  detect_kernel<<<1, 256, 0, stream>>>((const unsigned int*)ei, flag);
  degree_kernel<<<(ET + 255) / 256, 256, 0, stream>>>(ei, flag, deg);
  scan_kernel<<<1, 1024, 0, stream>>>(deg, rowptr, cursor);
  fill_kernel<<<(ET + 255) / 256, 256, 0, stream>>>(ei, flag, cursor, csr_src, csr_dst);

  // dtype prep
  conv_x_kernel<<<(NN * FDIM / 4 + 255) / 256, 256, 0, stream>>>(x, xb);
  for (int L = 0; L < 3; L++)
    conv_w_kernel<<<256, 256, 0, stream>>>(W[L], Wt[L]);

  const ushort* lin = xb;
  for (int L = 0; L < 3; L++) {
    gemm_bf16<<<dim3((NN + 127) / 128, 2), 256, 0, stream>>>(lin, Wt[L], hb);
    sd_kernel<<<NN, 256, 0, stream>>>(hb, as_[L], ad_[L], s_arr, d_arr);
    edgew_kernel<<<(ET + 255) / 256, 256, 0, stream>>>(csr_src, csr_dst, s_arr, d_arr, wt_arr);
    hipMemsetAsync(colsum, 0, 2048, stream);
    if (L < 2) {
      agg_kernel<true><<<NN, 256, 0, stream>>>(hb, wt_arr, rowptr, csr_src, b_[L], aggb);
      norm_reduce_bf<<<(NN + 127) / 128, 256, 0, stream>>>(aggb, colsum, colsumsq);
      norm_apply_bf<<<1024, 256, 0, stream>>>(aggb, yb, colsum, colsumsq, ga[L], gw[L], gb[L]);
      lin = yb;
    } else {
      agg_kernel<false><<<NN, 256, 0, stream>>>(hb, wt_arr, rowptr, csr_src, b_[L], bufD);
      norm_reduce_f32<<<(NN + 127) / 128, 256, 0, stream>>>(bufD, colsum, colsumsq);
      norm_apply_f32<<<512, 256, 0, stream>>>(bufD, colsum, colsumsq, ga[L], gw[L], gb[L]);
    }
  }
  mlp_kernel<<<(NN + 255) / 256, 256, 0, stream>>>(bufD, mW0, mb0, mW1, mb1, mW2, mb2, out);
}

// Round 4
// 812.395 us; speedup vs baseline: 2.3281x; 1.2760x over previous
//
#include <hip/hip_runtime.h>

#define NN 50000
#define EE 800000
#define ET 850000   // EE + NN self loops
#define HH 4
#define CC 64
#define FDIM 256    // HH*CC

typedef unsigned short ushort;
typedef __bf16 bf16x8 __attribute__((ext_vector_type(8)));
typedef float floatx4 __attribute__((ext_vector_type(4)));
typedef ushort ushort8v __attribute__((ext_vector_type(8)));
struct ushort4s { ushort x, y, z, w; };

__device__ __forceinline__ ushort f2bf(float f) {
  union { float f; unsigned u; } v; v.f = f;
  unsigned r = v.u + 0x7fffu + ((v.u >> 16) & 1u);  // RNE
  return (ushort)(r >> 16);
}
__device__ __forceinline__ float bf2f(ushort u) {
  return __uint_as_float(((unsigned)u) << 16);
}

// ---------- edge-index dtype handling (int32 vs int64 at runtime) ----------
__device__ __forceinline__ int get_edge(const void* p, int is64, long long idx) {
  if (is64) return (int)((const long long*)p)[idx];
  return ((const int*)p)[idx];
}

__global__ void detect_kernel(const unsigned int* p, int* flag) {
  // int64 with values < 50000 => every odd 32-bit word is 0
  __shared__ unsigned red[256];
  int t = threadIdx.x;
  unsigned o = 0;
  for (int i = 0; i < 4; i++) o |= p[(t * 4 + i) * 2 + 1];
  red[t] = o;
  __syncthreads();
  for (int s = 128; s > 0; s >>= 1) {
    if (t < s) red[t] |= red[t + s];
    __syncthreads();
  }
  if (t == 0) *flag = (red[0] == 0) ? 1 : 0;
}

// ---------- CSR build over dst ----------
__global__ void degree_kernel(const void* eidx, const int* flag, int* deg) {
  int k = blockIdx.x * blockDim.x + threadIdx.x;
  if (k >= ET) return;
  int is64 = *flag;
  int dst = (k < EE) ? get_edge(eidx, is64, (long long)EE + k) : (k - EE);
  atomicAdd(&deg[dst], 1);
}

__global__ __launch_bounds__(1024) void scan_kernel(const int* deg, int* rowptr, int* cursor) {
  __shared__ int partial[1024];
  int t = threadIdx.x;
  const int chunk = (NN + 1023) / 1024;
  int start = t * chunk;
  int end = min(start + chunk, NN);
  int sum = 0;
  for (int i = start; i < end; i++) sum += deg[i];
  partial[t] = sum;
  __syncthreads();
  for (int o = 1; o < 1024; o <<= 1) {
    int v = (t >= o) ? partial[t - o] : 0;
    __syncthreads();
    partial[t] += v;
    __syncthreads();
  }
  int run = (t == 0) ? 0 : partial[t - 1];
  for (int i = start; i < end; i++) {
    rowptr[i] = run; cursor[i] = run; run += deg[i];
  }
  if (t == 1023) rowptr[NN] = partial[1023];
}

__global__ void fill_kernel(const void* eidx, const int* flag, int* cursor, int* csr_src) {
  int k = blockIdx.x * blockDim.x + threadIdx.x;
  if (k >= ET) return;
  int is64 = *flag;
  int src, dst;
  if (k < EE) {
    src = get_edge(eidx, is64, k);
    dst = get_edge(eidx, is64, (long long)EE + k);
  } else {
    src = dst = k - EE;
  }
  int pos = atomicAdd(&cursor[dst], 1);
  csr_src[pos] = src;
}

// ---------- dtype conversions ----------
__global__ void conv_x_kernel(const float* __restrict__ x, ushort* __restrict__ xb) {
  int i = blockIdx.x * 256 + threadIdx.x;
  float4 v = ((const float4*)x)[i];
  ushort4s o;
  o.x = f2bf(v.x); o.y = f2bf(v.y); o.z = f2bf(v.z); o.w = f2bf(v.w);
  ((ushort4s*)xb)[i] = o;
}

__global__ void conv_w_kernel(const float* __restrict__ W, ushort* __restrict__ Wt) {
  int idx = blockIdx.x * 256 + threadIdx.x;  // 65536
  int k = idx >> 8, n = idx & 255;
  Wt[n * 256 + k] = f2bf(W[idx]);  // transpose: Wt[n][k]
}

// ---------- bf16 MFMA GEMM: C[M,256] = A[M,256] @ B[256,256], B given transposed ----------
__global__ __launch_bounds__(256) void gemm_bf16(const ushort* __restrict__ A,
                                                 const ushort* __restrict__ Bt,
                                                 ushort* __restrict__ C) {
  __shared__ ushort As[8 * 512];
  __shared__ ushort Bs[8 * 512];
  int tid = threadIdx.x, w = tid >> 6, l = tid & 63;
  int brow0 = blockIdx.x * 128, bcol0 = blockIdx.y * 128;
  int lm = l & 15, lk = (l >> 4) * 8;
  int s0 = 2 * w, s1 = 2 * w + 1;
  int ar0 = min(brow0 + s0 * 16 + lm, NN - 1);
  int ar1 = min(brow0 + s1 * 16 + lm, NN - 1);
  const ushort* ag0 = A + (size_t)ar0 * 256 + lk;
  const ushort* ag1 = A + (size_t)ar1 * 256 + lk;
  const ushort* bg0 = Bt + (size_t)(bcol0 + s0 * 16 + lm) * 256 + lk;
  const ushort* bg1 = Bt + (size_t)(bcol0 + s1 * 16 + lm) * 256 + lk;

  floatx4 acc[4][4];
#pragma unroll
  for (int i = 0; i < 4; i++)
#pragma unroll
    for (int j = 0; j < 4; j++) acc[i][j] = floatx4{0.f, 0.f, 0.f, 0.f};

  int wm = (w >> 1) * 4, wn = (w & 1) * 4;

  for (int k0 = 0; k0 < 256; k0 += 32) {
    ushort8v a0 = *(const ushort8v*)(ag0 + k0);
    ushort8v a1 = *(const ushort8v*)(ag1 + k0);
    ushort8v b0 = *(const ushort8v*)(bg0 + k0);
    ushort8v b1 = *(const ushort8v*)(bg1 + k0);
    *(ushort8v*)&As[s0 * 512 + l * 8] = a0;
    *(ushort8v*)&As[s1 * 512 + l * 8] = a1;
    *(ushort8v*)&Bs[s0 * 512 + l * 8] = b0;
    *(ushort8v*)&Bs[s1 * 512 + l * 8] = b1;
    __syncthreads();
    bf16x8 af[4], bfr[4];
#pragma unroll
    for (int i = 0; i < 4; i++) af[i] = *(const bf16x8*)&As[(wm + i) * 512 + l * 8];
#pragma unroll
    for (int j = 0; j < 4; j++) bfr[j] = *(const bf16x8*)&Bs[(wn + j) * 512 + l * 8];
#pragma unroll
    for (int i = 0; i < 4; i++)
#pragma unroll
      for (int j = 0; j < 4; j++)
        acc[i][j] = __builtin_amdgcn_mfma_f32_16x16x32_bf16(af[i], bfr[j], acc[i][j], 0, 0, 0);
    __syncthreads();
  }

  int quad = l >> 4;
#pragma unroll
  for (int i = 0; i < 4; i++) {
    int r0 = brow0 + (wm + i) * 16 + quad * 4;
#pragma unroll
    for (int j = 0; j < 4; j++) {
      int col = bcol0 + (wn + j) * 16 + lm;
#pragma unroll
      for (int r = 0; r < 4; r++) {
        int row = r0 + r;
        if (row < NN) C[(size_t)row * 256 + col] = f2bf(acc[i][j][r]);
      }
    }
  }
}

// ---------- attention logits s,d: one wave per node, lane l = channels [4l,4l+4) ----------
__global__ __launch_bounds__(256) void sd_kernel(const ushort* __restrict__ h,
                                                 const float* __restrict__ as_,
                                                 const float* __restrict__ ad_,
                                                 float* __restrict__ s, float* __restrict__ d) {
  int w = threadIdx.x >> 6;
  int l = threadIdx.x & 63;
  int n = blockIdx.x * 4 + w;
  ushort4s hv = *(const ushort4s*)(h + (size_t)n * FDIM + l * 4);
  float4 av = ((const float4*)as_)[l];
  float4 dv = ((const float4*)ad_)[l];
  float f0 = bf2f(hv.x), f1 = bf2f(hv.y), f2 = bf2f(hv.z), f3 = bf2f(hv.w);
  float ps = f0 * av.x + f1 * av.y + f2 * av.z + f3 * av.w;
  float pd = f0 * dv.x + f1 * dv.y + f2 * dv.z + f3 * dv.w;
#pragma unroll
  for (int o = 1; o < 16; o <<= 1) {
    ps += __shfl_xor(ps, o);
    pd += __shfl_xor(pd, o);
  }
  if ((l & 15) == 0) {
    s[n * HH + (l >> 4)] = ps;
    d[n * HH + (l >> 4)] = pd;
  }
}

// ---------- aggregation: one wave per node, all heads; fused edge softmax ----------
// lane l: head=l>>4, channels [4l,4l+4). Per edge: uniform s_load of src,
// 4-B per-lane load of s_arr[src*4+head], 8-B gather of h-row.
template <bool CONCAT>
__global__ __launch_bounds__(256) void agg_kernel(const ushort* __restrict__ hb,
                                                  const float* __restrict__ s_arr,
                                                  const float* __restrict__ d_arr,
                                                  const int* __restrict__ rowptr,
                                                  const int* __restrict__ csr_src,
                                                  const float* __restrict__ bias,
                                                  void* __restrict__ outp) {
  int w = __builtin_amdgcn_readfirstlane(threadIdx.x >> 6);
  int l = threadIdx.x & 63;
  int head = l >> 4;
  int n = blockIdx.x * 4 + w;
  int beg = rowptr[n], end = rowptr[n + 1];
  float dh = d_arr[n * HH + head];  // wave-uniform row, per-lane head select
  float a0 = 0.f, a1 = 0.f, a2 = 0.f, a3 = 0.f, den = 0.f;

  int i = beg;
  for (; i + 4 <= end; i += 4) {
    int s0 = csr_src[i], s1 = csr_src[i + 1], s2 = csr_src[i + 2], s3 = csr_src[i + 3];
    float e0 = s_arr[s0 * HH + head] + dh;
    float e1 = s_arr[s1 * HH + head] + dh;
    float e2 = s_arr[s2 * HH + head] + dh;
    float e3 = s_arr[s3 * HH + head] + dh;
    ushort4s h0 = *(const ushort4s*)(hb + (unsigned)(s0 * FDIM + l * 4));
    ushort4s h1 = *(const ushort4s*)(hb + (unsigned)(s1 * FDIM + l * 4));
    ushort4s h2 = *(const ushort4s*)(hb + (unsigned)(s2 * FDIM + l * 4));
    ushort4s h3 = *(const ushort4s*)(hb + (unsigned)(s3 * FDIM + l * 4));
    e0 = (e0 > 0.f) ? e0 : 0.2f * e0;  float w0 = __expf(e0);
    e1 = (e1 > 0.f) ? e1 : 0.2f * e1;  float w1 = __expf(e1);
    e2 = (e2 > 0.f) ? e2 : 0.2f * e2;  float w2 = __expf(e2);
    e3 = (e3 > 0.f) ? e3 : 0.2f * e3;  float w3 = __expf(e3);
    den += (w0 + w1) + (w2 + w3);
    a0 = fmaf(w0, bf2f(h0.x), a0); a1 = fmaf(w0, bf2f(h0.y), a1);
    a2 = fmaf(w0, bf2f(h0.z), a2); a3 = fmaf(w0, bf2f(h0.w), a3);
    a0 = fmaf(w1, bf2f(h1.x), a0); a1 = fmaf(w1, bf2f(h1.y), a1);
    a2 = fmaf(w1, bf2f(h1.z), a2); a3 = fmaf(w1, bf2f(h1.w), a3);
    a0 = fmaf(w2, bf2f(h2.x), a0); a1 = fmaf(w2, bf2f(h2.y), a1);
    a2 = fmaf(w2, bf2f(h2.z), a2); a3 = fmaf(w2, bf2f(h2.w), a3);
    a0 = fmaf(w3, bf2f(h3.x), a0); a1 = fmaf(w3, bf2f(h3.y), a1);
    a2 = fmaf(w3, bf2f(h3.z), a2); a3 = fmaf(w3, bf2f(h3.w), a3);
  }
  for (; i < end; i++) {
    int s0 = csr_src[i];
    float e0 = s_arr[s0 * HH + head] + dh;
    ushort4s h0 = *(const ushort4s*)(hb + (unsigned)(s0 * FDIM + l * 4));
    e0 = (e0 > 0.f) ? e0 : 0.2f * e0;
    float w0 = __expf(e0);
    den += w0;
    a0 = fmaf(w0, bf2f(h0.x), a0); a1 = fmaf(w0, bf2f(h0.y), a1);
    a2 = fmaf(w0, bf2f(h0.z), a2); a3 = fmaf(w0, bf2f(h0.w), a3);
  }
  float inv = 1.0f / den;  // self loop guarantees den > 0
  float r0 = a0 * inv, r1 = a1 * inv, r2 = a2 * inv, r3 = a3 * inv;

  if (CONCAT) {
    float4 bv = ((const float4*)bias)[l];
    ushort4s o;
    o.x = f2bf(r0 + bv.x); o.y = f2bf(r1 + bv.y);
    o.z = f2bf(r2 + bv.z); o.w = f2bf(r3 + bv.w);
    ((ushort4s*)outp)[(unsigned)(n * 64 + l)] = o;
  } else {
    // mean over heads: sum lanes {m, m+16, m+32, m+48}
    r0 += __shfl_xor(r0, 16); r1 += __shfl_xor(r1, 16);
    r2 += __shfl_xor(r2, 16); r3 += __shfl_xor(r3, 16);
    r0 += __shfl_xor(r0, 32); r1 += __shfl_xor(r1, 32);
    r2 += __shfl_xor(r2, 32); r3 += __shfl_xor(r3, 32);
    if (l < 16) {
      float4 bv = ((const float4*)bias)[l];
      float4 o;
      o.x = 0.25f * r0 + bv.x; o.y = 0.25f * r1 + bv.y;
      o.z = 0.25f * r2 + bv.z; o.w = 0.25f * r3 + bv.w;
      ((float4*)outp)[(unsigned)(n * 16 + l)] = o;
    }
  }
}

// ---------- GraphNorm ----------
__global__ __launch_bounds__(256) void norm_reduce_bf(const ushort* __restrict__ xin,
                                                      float* colsum, float* colsumsq) {
  int f = threadIdx.x;
  int r0 = blockIdx.x * 128;
  int r1 = min(NN, r0 + 128);
  float s1 = 0.f, s2 = 0.f;
  for (int r = r0; r < r1; r++) {
    float v = bf2f(xin[(size_t)r * FDIM + f]);
    s1 += v; s2 += v * v;
  }
  atomicAdd(&colsum[f], s1);
  atomicAdd(&colsumsq[f], s2);
}

__global__ __launch_bounds__(256) void norm_reduce_f32(const float* __restrict__ xin,
                                                       float* colsum, float* colsumsq) {
  int f = threadIdx.x & (CC - 1);
  int rl = threadIdx.x / CC;
  int r0 = blockIdx.x * 128;
  int r1 = min(NN, r0 + 128);
  float s1 = 0.f, s2 = 0.f;
  for (int r = r0 + rl; r < r1; r += 4) {
    float v = xin[(size_t)r * CC + f];
    s1 += v; s2 += v * v;
  }
  atomicAdd(&colsum[f], s1);
  atomicAdd(&colsumsq[f], s2);
}

// finalize folded in: each block recomputes scale/shift, then grid-stride apply
__global__ __launch_bounds__(256) void norm_apply_bf(const ushort* __restrict__ in,
                                                     ushort* __restrict__ outb,
                                                     const float* __restrict__ colsum,
                                                     const float* __restrict__ colsumsq,
                                                     const float* __restrict__ ga,
                                                     const float* __restrict__ gw,
                                                     const float* __restrict__ gb) {
  __shared__ float sc[FDIM], sh[FDIM];
  int t = threadIdx.x;
  {
    const float invn = 1.0f / (float)NN;
    float mu = colsum[t] * invn;
    float ex2 = colsumsq[t] * invn;
    float a = ga[t];
    float var = fmaxf(ex2 - (2.f * a - a * a) * mu * mu, 0.f);
    float s = gw[t] * rsqrtf(var + 1e-5f);
    sc[t] = s; sh[t] = gb[t] - s * a * mu;
  }
  __syncthreads();
  const int total = NN * FDIM / 4;
  for (int i = blockIdx.x * 256 + t; i < total; i += gridDim.x * 256) {
    int f0 = (i * 4) & (FDIM - 1);
    ushort4s v = ((const ushort4s*)in)[i];
    float y0 = sc[f0 + 0] * bf2f(v.x) + sh[f0 + 0];
    float y1 = sc[f0 + 1] * bf2f(v.y) + sh[f0 + 1];
    float y2 = sc[f0 + 2] * bf2f(v.z) + sh[f0 + 2];
    float y3 = sc[f0 + 3] * bf2f(v.w) + sh[f0 + 3];
    ushort4s o;
    o.x = f2bf((y0 > 0.f) ? y0 : 0.01f * y0);
    o.y = f2bf((y1 > 0.f) ? y1 : 0.01f * y1);
    o.z = f2bf((y2 > 0.f) ? y2 : 0.01f * y2);
    o.w = f2bf((y3 > 0.f) ? y3 : 0.01f * y3);
    ((ushort4s*)outb)[i] = o;
  }
}

__global__ __launch_bounds__(256) void norm_apply_f32(float* __restrict__ xio,
                                                      const float* __restrict__ colsum,
                                                      const float* __restrict__ colsumsq,
                                                      const float* __restrict__ ga,
                                                      const float* __restrict__ gw,
                                                      const float* __restrict__ gb) {
  __shared__ float sc[CC], sh[CC];
  int t = threadIdx.x;
  if (t < CC) {
    const float invn = 1.0f / (float)NN;
    float mu = colsum[t] * invn;
    float ex2 = colsumsq[t] * invn;
    float a = ga[t];
    float var = fmaxf(ex2 - (2.f * a - a * a) * mu * mu, 0.f);
    float s = gw[t] * rsqrtf(var + 1e-5f);
    sc[t] = s; sh[t] = gb[t] - s * a * mu;
  }
  __syncthreads();
  const int total = NN * CC;
  for (int i = blockIdx.x * 256 + t; i < total; i += gridDim.x * 256) {
    int f = i & (CC - 1);
    float y = sc[f] * xio[i] + sh[f];
    xio[i] = (y > 0.f) ? y : 0.01f * y;
  }
}

// ---------- MLP 64->32->16->2, weights in LDS, one thread per node ----------
__global__ __launch_bounds__(256) void mlp_kernel(const float* __restrict__ xin,
                                                  const float* mW0, const float* mb0,
                                                  const float* mW1, const float* mb1,
                                                  const float* mW2, const float* mb2,
                                                  float* __restrict__ out) {
  __shared__ float W0s[64 * 32];
  __shared__ float W1s[32 * 16];
  __shared__ float W2s[16 * 2];
  __shared__ float b0s[32], b1s[16], b2s[2];
  int t = threadIdx.x;
  for (int i = t; i < 2048; i += 256) W0s[i] = mW0[i];
  for (int i = t; i < 512; i += 256) W1s[i] = mW1[i];
  if (t < 32) { W2s[t] = mW2[t]; b0s[t] = mb0[t]; }
  if (t < 16) b1s[t] = mb1[t];
  if (t < 2) b2s[t] = mb2[t];
  __syncthreads();
  int node = blockIdx.x * 256 + t;
  if (node >= NN) return;
  float in[64];
  const float* xr = xin + (size_t)node * 64;
#pragma unroll
  for (int k = 0; k < 64; k++) in[k] = xr[k];
  float h1[32];
#pragma unroll
  for (int j = 0; j < 32; j++) h1[j] = b0s[j];
#pragma unroll
  for (int k = 0; k < 64; k++) {
    float v = in[k];
#pragma unroll
    for (int j = 0; j < 32; j++) h1[j] += v * W0s[k * 32 + j];
  }
#pragma unroll
  for (int j = 0; j < 32; j++) h1[j] = fmaxf(h1[j], 0.f);
  float h2[16];
#pragma unroll
  for (int j = 0; j < 16; j++) h2[j] = b1s[j];
#pragma unroll
  for (int k = 0; k < 32; k++) {
    float v = h1[k];
#pragma unroll
    for (int j = 0; j < 16; j++) h2[j] += v * W1s[k * 16 + j];
  }
#pragma unroll
  for (int j = 0; j < 16; j++) h2[j] = fmaxf(h2[j], 0.f);
  float o0 = b2s[0], o1 = b2s[1];
#pragma unroll
  for (int k = 0; k < 16; k++) {
    o0 += h2[k] * W2s[k * 2 + 0];
    o1 += h2[k] * W2s[k * 2 + 1];
  }
  out[(size_t)node * 2 + 0] = o0;
  out[(size_t)node * 2 + 1] = o1;
}

extern "C" void kernel_launch(void* const* d_in, const int* in_sizes, int n_in,
                              void* d_out, int out_size, void* d_ws, size_t ws_size,
                              hipStream_t stream) {
  const float* x = (const float*)d_in[0];
  const void* ei = d_in[1];
  const float* W[3]   = {(const float*)d_in[2],  (const float*)d_in[9],  (const float*)d_in[16]};
  const float* as_[3] = {(const float*)d_in[3],  (const float*)d_in[10], (const float*)d_in[17]};
  const float* ad_[3] = {(const float*)d_in[4],  (const float*)d_in[11], (const float*)d_in[18]};
  const float* b_[3]  = {(const float*)d_in[5],  (const float*)d_in[12], (const float*)d_in[19]};
  const float* gw[3]  = {(const float*)d_in[6],  (const float*)d_in[13], (const float*)d_in[20]};
  const float* gb[3]  = {(const float*)d_in[7],  (const float*)d_in[14], (const float*)d_in[21]};
  const float* ga[3]  = {(const float*)d_in[8],  (const float*)d_in[15], (const float*)d_in[22]};
  const float* mW0 = (const float*)d_in[23];
  const float* mb0 = (const float*)d_in[24];
  const float* mW1 = (const float*)d_in[25];
  const float* mb1 = (const float*)d_in[26];
  const float* mW2 = (const float*)d_in[27];
  const float* mb2 = (const float*)d_in[28];
  float* out = (float*)d_out;

  char* ws = (char*)d_ws;
  size_t off = 0;
  auto take = [&](size_t bytes) -> char* {
    char* p = ws + off;
    off = (off + bytes + 255) & ~(size_t)255;
    return p;
  };
  ushort* xb    = (ushort*)take((size_t)NN * FDIM * 2);
  ushort* hb    = (ushort*)take((size_t)NN * FDIM * 2);
  ushort* yb    = (ushort*)take((size_t)NN * FDIM * 2);
  ushort* aggb  = (ushort*)take((size_t)NN * FDIM * 2);
  float* bufD   = (float*)take((size_t)NN * CC * 4);
  ushort* Wt[3];
  for (int i = 0; i < 3; i++) Wt[i] = (ushort*)take((size_t)256 * 256 * 2);
  float* s_arr  = (float*)take((size_t)NN * HH * 4);
  float* d_arr  = (float*)take((size_t)NN * HH * 4);
  int* deg      = (int*)take((size_t)NN * 4);
  int* cursor   = (int*)take((size_t)NN * 4);
  int* rowptr   = (int*)take((size_t)(NN + 1) * 4);
  int* csr_src  = (int*)take((size_t)ET * 4);
  float* colsum   = (float*)take(1024);   // colsum+colsumsq contiguous: one memset
  float* colsumsq = (float*)take(1024);
  int* flag       = (int*)take(256);

  // CSR build (reused by all 3 layers)
  hipMemsetAsync(deg, 0, (size_t)NN * 4, stream);
  detect_kernel<<<1, 256, 0, stream>>>((const unsigned int*)ei, flag);
  degree_kernel<<<(ET + 255) / 256, 256, 0, stream>>>(ei, flag, deg);
  scan_kernel<<<1, 1024, 0, stream>>>(deg, rowptr, cursor);
  fill_kernel<<<(ET + 255) / 256, 256, 0, stream>>>(ei, flag, cursor, csr_src);

  // dtype prep
  conv_x_kernel<<<(NN * FDIM / 4 + 255) / 256, 256, 0, stream>>>(x, xb);
  for (int L = 0; L < 3; L++)
    conv_w_kernel<<<256, 256, 0, stream>>>(W[L], Wt[L]);

  const ushort* lin = xb;
  for (int L = 0; L < 3; L++) {
    gemm_bf16<<<dim3((NN + 127) / 128, 2), 256, 0, stream>>>(lin, Wt[L], hb);
    sd_kernel<<<NN / 4, 256, 0, stream>>>(hb, as_[L], ad_[L], s_arr, d_arr);
    hipMemsetAsync(colsum, 0, 2048, stream);
    if (L < 2) {
      agg_kernel<true><<<NN / 4, 256, 0, stream>>>(hb, s_arr, d_arr, rowptr, csr_src, b_[L], aggb);
      norm_reduce_bf<<<(NN + 127) / 128, 256, 0, stream>>>(aggb, colsum, colsumsq);
      norm_apply_bf<<<1024, 256, 0, stream>>>(aggb, yb, colsum, colsumsq, ga[L], gw[L], gb[L]);
      lin = yb;
    } else {
      agg_kernel<false><<<NN / 4, 256, 0, stream>>>(hb, s_arr, d_arr, rowptr, csr_src, b_[L], bufD);
      norm_reduce_f32<<<(NN + 127) / 128, 256, 0, stream>>>(bufD, colsum, colsumsq);
      norm_apply_f32<<<512, 256, 0, stream>>>(bufD, colsum, colsumsq, ga[L], gw[L], gb[L]);
    }
  }
  mlp_kernel<<<(NN + 255) / 256, 256, 0, stream>>>(bufD, mW0, mb0, mW1, mb1, mW2, mb2, out);
}

// Round 5
// 714.304 us; speedup vs baseline: 2.6478x; 1.1373x over previous
//
#include <hip/hip_runtime.h>

#define NN 50000
#define EE 800000
#define ET 850000   // EE + NN self loops
#define HH 4
#define CC 64
#define FDIM 256    // HH*CC

#define SCAN_BLK 512
#define SCAN_NB ((NN + SCAN_BLK - 1) / SCAN_BLK)   // 98

typedef unsigned short ushort;
typedef __bf16 bf16x8 __attribute__((ext_vector_type(8)));
typedef float floatx4 __attribute__((ext_vector_type(4)));
typedef ushort ushort8v __attribute__((ext_vector_type(8)));
struct ushort4s { ushort x, y, z, w; };

__device__ __forceinline__ ushort f2bf(float f) {
  union { float f; unsigned u; } v; v.f = f;
  unsigned r = v.u + 0x7fffu + ((v.u >> 16) & 1u);  // RNE
  return (ushort)(r >> 16);
}
__device__ __forceinline__ float bf2f(ushort u) {
  return __uint_as_float(((unsigned)u) << 16);
}

// ---------- edge-index dtype handling (int32 vs int64 at runtime) ----------
__device__ __forceinline__ int get_edge(const void* p, int is64, long long idx) {
  if (is64) return (int)((const long long*)p)[idx];
  return ((const int*)p)[idx];
}

__global__ void detect_kernel(const unsigned int* p, int* flag) {
  // int64 with values < 50000 => every odd 32-bit word is 0
  __shared__ unsigned red[256];
  int t = threadIdx.x;
  unsigned o = 0;
  for (int i = 0; i < 4; i++) o |= p[(t * 4 + i) * 2 + 1];
  red[t] = o;
  __syncthreads();
  for (int s = 128; s > 0; s >>= 1) {
    if (t < s) red[t] |= red[t + s];
    __syncthreads();
  }
  if (t == 0) *flag = (red[0] == 0) ? 1 : 0;
}

// ---------- CSR build over dst ----------
__global__ void degree_kernel(const void* eidx, const int* flag, int* deg) {
  int k = blockIdx.x * blockDim.x + threadIdx.x;
  if (k >= ET) return;
  int is64 = *flag;
  int dst = (k < EE) ? get_edge(eidx, is64, (long long)EE + k) : (k - EE);
  atomicAdd(&deg[dst], 1);
}

// 3-phase parallel exclusive scan of deg -> rowptr/cursor.
// Phase 1: per-block (512-wide) LDS Hillis-Steele scan, coalesced; local exclusive
//          to rowptr, block total to bsum.
__global__ __launch_bounds__(SCAN_BLK) void scan1_kernel(const int* __restrict__ deg,
                                                         int* __restrict__ rowptr,
                                                         int* __restrict__ bsum) {
  __shared__ int sm[SCAN_BLK];
  int t = threadIdx.x;
  int i = blockIdx.x * SCAN_BLK + t;
  int v = (i < NN) ? deg[i] : 0;
  sm[t] = v;
  __syncthreads();
#pragma unroll
  for (int o = 1; o < SCAN_BLK; o <<= 1) {
    int u = (t >= o) ? sm[t - o] : 0;
    __syncthreads();
    sm[t] += u;
    __syncthreads();
  }
  if (i < NN) rowptr[i] = sm[t] - v;                 // local exclusive
  if (t == SCAN_BLK - 1) bsum[blockIdx.x] = sm[t];   // block total
}

// Phase 2: scan the 98 block sums (one tiny block); rowptr[NN] = ET (known constant).
__global__ __launch_bounds__(128) void scan2_kernel(const int* __restrict__ bsum,
                                                    int* __restrict__ boff,
                                                    int* __restrict__ rowptr) {
  __shared__ int sm[128];
  int t = threadIdx.x;
  int v = (t < SCAN_NB) ? bsum[t] : 0;
  sm[t] = v;
  __syncthreads();
#pragma unroll
  for (int o = 1; o < 128; o <<= 1) {
    int u = (t >= o) ? sm[t - o] : 0;
    __syncthreads();
    sm[t] += u;
    __syncthreads();
  }
  if (t < SCAN_NB) boff[t] = sm[t] - v;  // exclusive block offset
  if (t == 0) rowptr[NN] = ET;
}

// Phase 3: add block offsets; init cursor.
__global__ __launch_bounds__(SCAN_BLK) void scan3_kernel(int* __restrict__ rowptr,
                                                         int* __restrict__ cursor,
                                                         const int* __restrict__ boff) {
  int i = blockIdx.x * SCAN_BLK + threadIdx.x;
  if (i >= NN) return;
  int v = rowptr[i] + boff[blockIdx.x];
  rowptr[i] = v;
  cursor[i] = v;
}

__global__ void fill_kernel(const void* eidx, const int* flag, int* cursor, int* csr_src) {
  int k = blockIdx.x * blockDim.x + threadIdx.x;
  if (k >= ET) return;
  int is64 = *flag;
  int src, dst;
  if (k < EE) {
    src = get_edge(eidx, is64, k);
    dst = get_edge(eidx, is64, (long long)EE + k);
  } else {
    src = dst = k - EE;
  }
  int pos = atomicAdd(&cursor[dst], 1);
  csr_src[pos] = src;
}

// ---------- dtype conversions ----------
__global__ void conv_x_kernel(const float* __restrict__ x, ushort* __restrict__ xb) {
  int i = blockIdx.x * 256 + threadIdx.x;
  float4 v = ((const float4*)x)[i];
  ushort4s o;
  o.x = f2bf(v.x); o.y = f2bf(v.y); o.z = f2bf(v.z); o.w = f2bf(v.w);
  ((ushort4s*)xb)[i] = o;
}

__global__ void conv_w_kernel(const float* __restrict__ W, ushort* __restrict__ Wt) {
  int idx = blockIdx.x * 256 + threadIdx.x;  // 65536
  int k = idx >> 8, n = idx & 255;
  Wt[n * 256 + k] = f2bf(W[idx]);  // transpose: Wt[n][k]
}

// ---------- bf16 MFMA GEMM: C[M,256] = A[M,256] @ B[256,256], B given transposed ----------
__global__ __launch_bounds__(256) void gemm_bf16(const ushort* __restrict__ A,
                                                 const ushort* __restrict__ Bt,
                                                 ushort* __restrict__ C) {
  __shared__ ushort As[8 * 512];
  __shared__ ushort Bs[8 * 512];
  int tid = threadIdx.x, w = tid >> 6, l = tid & 63;
  int brow0 = blockIdx.x * 128, bcol0 = blockIdx.y * 128;
  int lm = l & 15, lk = (l >> 4) * 8;
  int s0 = 2 * w, s1 = 2 * w + 1;
  int ar0 = min(brow0 + s0 * 16 + lm, NN - 1);
  int ar1 = min(brow0 + s1 * 16 + lm, NN - 1);
  const ushort* ag0 = A + (size_t)ar0 * 256 + lk;
  const ushort* ag1 = A + (size_t)ar1 * 256 + lk;
  const ushort* bg0 = Bt + (size_t)(bcol0 + s0 * 16 + lm) * 256 + lk;
  const ushort* bg1 = Bt + (size_t)(bcol0 + s1 * 16 + lm) * 256 + lk;

  floatx4 acc[4][4];
#pragma unroll
  for (int i = 0; i < 4; i++)
#pragma unroll
    for (int j = 0; j < 4; j++) acc[i][j] = floatx4{0.f, 0.f, 0.f, 0.f};

  int wm = (w >> 1) * 4, wn = (w & 1) * 4;

  for (int k0 = 0; k0 < 256; k0 += 32) {
    ushort8v a0 = *(const ushort8v*)(ag0 + k0);
    ushort8v a1 = *(const ushort8v*)(ag1 + k0);
    ushort8v b0 = *(const ushort8v*)(bg0 + k0);
    ushort8v b1 = *(const ushort8v*)(bg1 + k0);
    *(ushort8v*)&As[s0 * 512 + l * 8] = a0;
    *(ushort8v*)&As[s1 * 512 + l * 8] = a1;
    *(ushort8v*)&Bs[s0 * 512 + l * 8] = b0;
    *(ushort8v*)&Bs[s1 * 512 + l * 8] = b1;
    __syncthreads();
    bf16x8 af[4], bfr[4];
#pragma unroll
    for (int i = 0; i < 4; i++) af[i] = *(const bf16x8*)&As[(wm + i) * 512 + l * 8];
#pragma unroll
    for (int j = 0; j < 4; j++) bfr[j] = *(const bf16x8*)&Bs[(wn + j) * 512 + l * 8];
#pragma unroll
    for (int i = 0; i < 4; i++)
#pragma unroll
      for (int j = 0; j < 4; j++)
        acc[i][j] = __builtin_amdgcn_mfma_f32_16x16x32_bf16(af[i], bfr[j], acc[i][j], 0, 0, 0);
    __syncthreads();
  }

  int quad = l >> 4;
#pragma unroll
  for (int i = 0; i < 4; i++) {
    int r0 = brow0 + (wm + i) * 16 + quad * 4;
#pragma unroll
    for (int j = 0; j < 4; j++) {
      int col = bcol0 + (wn + j) * 16 + lm;
#pragma unroll
      for (int r = 0; r < 4; r++) {
        int row = r0 + r;
        if (row < NN) C[(size_t)row * 256 + col] = f2bf(acc[i][j][r]);
      }
    }
  }
}

// ---------- attention logits s,d: one wave per node, lane l = channels [4l,4l+4) ----------
__global__ __launch_bounds__(256) void sd_kernel(const ushort* __restrict__ h,
                                                 const float* __restrict__ as_,
                                                 const float* __restrict__ ad_,
                                                 float* __restrict__ s, float* __restrict__ d) {
  int w = threadIdx.x >> 6;
  int l = threadIdx.x & 63;
  int n = blockIdx.x * 4 + w;
  ushort4s hv = *(const ushort4s*)(h + (size_t)n * FDIM + l * 4);
  float4 av = ((const float4*)as_)[l];
  float4 dv = ((const float4*)ad_)[l];
  float f0 = bf2f(hv.x), f1 = bf2f(hv.y), f2 = bf2f(hv.z), f3 = bf2f(hv.w);
  float ps = f0 * av.x + f1 * av.y + f2 * av.z + f3 * av.w;
  float pd = f0 * dv.x + f1 * dv.y + f2 * dv.z + f3 * dv.w;
#pragma unroll
  for (int o = 1; o < 16; o <<= 1) {
    ps += __shfl_xor(ps, o);
    pd += __shfl_xor(pd, o);
  }
  if ((l & 15) == 0) {
    s[n * HH + (l >> 4)] = ps;
    d[n * HH + (l >> 4)] = pd;
  }
}

// ---------- aggregation: one wave per node, all heads; fused edge softmax ----------
template <bool CONCAT>
__global__ __launch_bounds__(256) void agg_kernel(const ushort* __restrict__ hb,
                                                  const float* __restrict__ s_arr,
                                                  const float* __restrict__ d_arr,
                                                  const int* __restrict__ rowptr,
                                                  const int* __restrict__ csr_src,
                                                  const float* __restrict__ bias,
                                                  void* __restrict__ outp) {
  int w = __builtin_amdgcn_readfirstlane(threadIdx.x >> 6);
  int l = threadIdx.x & 63;
  int head = l >> 4;
  int n = blockIdx.x * 4 + w;
  int beg = rowptr[n], end = rowptr[n + 1];
  float dh = d_arr[n * HH + head];  // wave-uniform row, per-lane head select
  float a0 = 0.f, a1 = 0.f, a2 = 0.f, a3 = 0.f, den = 0.f;

  int i = beg;
  for (; i + 4 <= end; i += 4) {
    int s0 = csr_src[i], s1 = csr_src[i + 1], s2 = csr_src[i + 2], s3 = csr_src[i + 3];
    float e0 = s_arr[s0 * HH + head] + dh;
    float e1 = s_arr[s1 * HH + head] + dh;
    float e2 = s_arr[s2 * HH + head] + dh;
    float e3 = s_arr[s3 * HH + head] + dh;
    ushort4s h0 = *(const ushort4s*)(hb + (unsigned)(s0 * FDIM + l * 4));
    ushort4s h1 = *(const ushort4s*)(hb + (unsigned)(s1 * FDIM + l * 4));
    ushort4s h2 = *(const ushort4s*)(hb + (unsigned)(s2 * FDIM + l * 4));
    ushort4s h3 = *(const ushort4s*)(hb + (unsigned)(s3 * FDIM + l * 4));
    e0 = (e0 > 0.f) ? e0 : 0.2f * e0;  float w0 = __expf(e0);
    e1 = (e1 > 0.f) ? e1 : 0.2f * e1;  float w1 = __expf(e1);
    e2 = (e2 > 0.f) ? e2 : 0.2f * e2;  float w2 = __expf(e2);
    e3 = (e3 > 0.f) ? e3 : 0.2f * e3;  float w3 = __expf(e3);
    den += (w0 + w1) + (w2 + w3);
    a0 = fmaf(w0, bf2f(h0.x), a0); a1 = fmaf(w0, bf2f(h0.y), a1);
    a2 = fmaf(w0, bf2f(h0.z), a2); a3 = fmaf(w0, bf2f(h0.w), a3);
    a0 = fmaf(w1, bf2f(h1.x), a0); a1 = fmaf(w1, bf2f(h1.y), a1);
    a2 = fmaf(w1, bf2f(h1.z), a2); a3 = fmaf(w1, bf2f(h1.w), a3);
    a0 = fmaf(w2, bf2f(h2.x), a0); a1 = fmaf(w2, bf2f(h2.y), a1);
    a2 = fmaf(w2, bf2f(h2.z), a2); a3 = fmaf(w2, bf2f(h2.w), a3);
    a0 = fmaf(w3, bf2f(h3.x), a0); a1 = fmaf(w3, bf2f(h3.y), a1);
    a2 = fmaf(w3, bf2f(h3.z), a2); a3 = fmaf(w3, bf2f(h3.w), a3);
  }
  for (; i < end; i++) {
    int s0 = csr_src[i];
    float e0 = s_arr[s0 * HH + head] + dh;
    ushort4s h0 = *(const ushort4s*)(hb + (unsigned)(s0 * FDIM + l * 4));
    e0 = (e0 > 0.f) ? e0 : 0.2f * e0;
    float w0 = __expf(e0);
    den += w0;
    a0 = fmaf(w0, bf2f(h0.x), a0); a1 = fmaf(w0, bf2f(h0.y), a1);
    a2 = fmaf(w0, bf2f(h0.z), a2); a3 = fmaf(w0, bf2f(h0.w), a3);
  }
  float inv = 1.0f / den;  // self loop guarantees den > 0
  float r0 = a0 * inv, r1 = a1 * inv, r2 = a2 * inv, r3 = a3 * inv;

  if (CONCAT) {
    float4 bv = ((const float4*)bias)[l];
    ushort4s o;
    o.x = f2bf(r0 + bv.x); o.y = f2bf(r1 + bv.y);
    o.z = f2bf(r2 + bv.z); o.w = f2bf(r3 + bv.w);
    ((ushort4s*)outp)[(unsigned)(n * 64 + l)] = o;
  } else {
    // mean over heads: sum lanes {m, m+16, m+32, m+48}
    r0 += __shfl_xor(r0, 16); r1 += __shfl_xor(r1, 16);
    r2 += __shfl_xor(r2, 16); r3 += __shfl_xor(r3, 16);
    r0 += __shfl_xor(r0, 32); r1 += __shfl_xor(r1, 32);
    r2 += __shfl_xor(r2, 32); r3 += __shfl_xor(r3, 32);
    if (l < 16) {
      float4 bv = ((const float4*)bias)[l];
      float4 o;
      o.x = 0.25f * r0 + bv.x; o.y = 0.25f * r1 + bv.y;
      o.z = 0.25f * r2 + bv.z; o.w = 0.25f * r3 + bv.w;
      ((float4*)outp)[(unsigned)(n * 16 + l)] = o;
    }
  }
}

// ---------- GraphNorm ----------
__global__ __launch_bounds__(256) void norm_reduce_bf(const ushort* __restrict__ xin,
                                                      float* colsum, float* colsumsq) {
  int f = threadIdx.x;
  int r0 = blockIdx.x * 128;
  int r1 = min(NN, r0 + 128);
  float s1 = 0.f, s2 = 0.f;
  for (int r = r0; r < r1; r++) {
    float v = bf2f(xin[(size_t)r * FDIM + f]);
    s1 += v; s2 += v * v;
  }
  atomicAdd(&colsum[f], s1);
  atomicAdd(&colsumsq[f], s2);
}

__global__ __launch_bounds__(256) void norm_reduce_f32(const float* __restrict__ xin,
                                                       float* colsum, float* colsumsq) {
  int f = threadIdx.x & (CC - 1);
  int rl = threadIdx.x / CC;
  int r0 = blockIdx.x * 128;
  int r1 = min(NN, r0 + 128);
  float s1 = 0.f, s2 = 0.f;
  for (int r = r0 + rl; r < r1; r += 4) {
    float v = xin[(size_t)r * CC + f];
    s1 += v; s2 += v * v;
  }
  atomicAdd(&colsum[f], s1);
  atomicAdd(&colsumsq[f], s2);
}

// finalize folded in: each block recomputes scale/shift, then grid-stride apply
__global__ __launch_bounds__(256) void norm_apply_bf(const ushort* __restrict__ in,
                                                     ushort* __restrict__ outb,
                                                     const float* __restrict__ colsum,
                                                     const float* __restrict__ colsumsq,
                                                     const float* __restrict__ ga,
                                                     const float* __restrict__ gw,
                                                     const float* __restrict__ gb) {
  __shared__ float sc[FDIM], sh[FDIM];
  int t = threadIdx.x;
  {
    const float invn = 1.0f / (float)NN;
    float mu = colsum[t] * invn;
    float ex2 = colsumsq[t] * invn;
    float a = ga[t];
    float var = fmaxf(ex2 - (2.f * a - a * a) * mu * mu, 0.f);
    float s = gw[t] * rsqrtf(var + 1e-5f);
    sc[t] = s; sh[t] = gb[t] - s * a * mu;
  }
  __syncthreads();
  const int total = NN * FDIM / 4;
  for (int i = blockIdx.x * 256 + t; i < total; i += gridDim.x * 256) {
    int f0 = (i * 4) & (FDIM - 1);
    ushort4s v = ((const ushort4s*)in)[i];
    float y0 = sc[f0 + 0] * bf2f(v.x) + sh[f0 + 0];
    float y1 = sc[f0 + 1] * bf2f(v.y) + sh[f0 + 1];
    float y2 = sc[f0 + 2] * bf2f(v.z) + sh[f0 + 2];
    float y3 = sc[f0 + 3] * bf2f(v.w) + sh[f0 + 3];
    ushort4s o;
    o.x = f2bf((y0 > 0.f) ? y0 : 0.01f * y0);
    o.y = f2bf((y1 > 0.f) ? y1 : 0.01f * y1);
    o.z = f2bf((y2 > 0.f) ? y2 : 0.01f * y2);
    o.w = f2bf((y3 > 0.f) ? y3 : 0.01f * y3);
    ((ushort4s*)outb)[i] = o;
  }
}

__global__ __launch_bounds__(256) void norm_apply_f32(float* __restrict__ xio,
                                                      const float* __restrict__ colsum,
                                                      const float* __restrict__ colsumsq,
                                                      const float* __restrict__ ga,
                                                      const float* __restrict__ gw,
                                                      const float* __restrict__ gb) {
  __shared__ float sc[CC], sh[CC];
  int t = threadIdx.x;
  if (t < CC) {
    const float invn = 1.0f / (float)NN;
    float mu = colsum[t] * invn;
    float ex2 = colsumsq[t] * invn;
    float a = ga[t];
    float var = fmaxf(ex2 - (2.f * a - a * a) * mu * mu, 0.f);
    float s = gw[t] * rsqrtf(var + 1e-5f);
    sc[t] = s; sh[t] = gb[t] - s * a * mu;
  }
  __syncthreads();
  const int total = NN * CC;
  for (int i = blockIdx.x * 256 + t; i < total; i += gridDim.x * 256) {
    int f = i & (CC - 1);
    float y = sc[f] * xio[i] + sh[f];
    xio[i] = (y > 0.f) ? y : 0.01f * y;
  }
}

// ---------- MLP 64->32->16->2, weights in LDS, one thread per node ----------
__global__ __launch_bounds__(256) void mlp_kernel(const float* __restrict__ xin,
                                                  const float* mW0, const float* mb0,
                                                  const float* mW1, const float* mb1,
                                                  const float* mW2, const float* mb2,
                                                  float* __restrict__ out) {
  __shared__ float W0s[64 * 32];
  __shared__ float W1s[32 * 16];
  __shared__ float W2s[16 * 2];
  __shared__ float b0s[32], b1s[16], b2s[2];
  int t = threadIdx.x;
  for (int i = t; i < 2048; i += 256) W0s[i] = mW0[i];
  for (int i = t; i < 512; i += 256) W1s[i] = mW1[i];
  if (t < 32) { W2s[t] = mW2[t]; b0s[t] = mb0[t]; }
  if (t < 16) b1s[t] = mb1[t];
  if (t < 2) b2s[t] = mb2[t];
  __syncthreads();
  int node = blockIdx.x * 256 + t;
  if (node >= NN) return;
  float in[64];
  const float* xr = xin + (size_t)node * 64;
#pragma unroll
  for (int k = 0; k < 64; k++) in[k] = xr[k];
  float h1[32];
#pragma unroll
  for (int j = 0; j < 32; j++) h1[j] = b0s[j];
#pragma unroll
  for (int k = 0; k < 64; k++) {
    float v = in[k];
#pragma unroll
    for (int j = 0; j < 32; j++) h1[j] += v * W0s[k * 32 + j];
  }
#pragma unroll
  for (int j = 0; j < 32; j++) h1[j] = fmaxf(h1[j], 0.f);
  float h2[16];
#pragma unroll
  for (int j = 0; j < 16; j++) h2[j] = b1s[j];
#pragma unroll
  for (int k = 0; k < 32; k++) {
    float v = h1[k];
#pragma unroll
    for (int j = 0; j < 16; j++) h2[j] += v * W1s[k * 16 + j];
  }
#pragma unroll
  for (int j = 0; j < 16; j++) h2[j] = fmaxf(h2[j], 0.f);
  float o0 = b2s[0], o1 = b2s[1];
#pragma unroll
  for (int k = 0; k < 16; k++) {
    o0 += h2[k] * W2s[k * 2 + 0];
    o1 += h2[k] * W2s[k * 2 + 1];
  }
  out[(size_t)node * 2 + 0] = o0;
  out[(size_t)node * 2 + 1] = o1;
}

extern "C" void kernel_launch(void* const* d_in, const int* in_sizes, int n_in,
                              void* d_out, int out_size, void* d_ws, size_t ws_size,
                              hipStream_t stream) {
  const float* x = (const float*)d_in[0];
  const void* ei = d_in[1];
  const float* W[3]   = {(const float*)d_in[2],  (const float*)d_in[9],  (const float*)d_in[16]};
  const float* as_[3] = {(const float*)d_in[3],  (const float*)d_in[10], (const float*)d_in[17]};
  const float* ad_[3] = {(const float*)d_in[4],  (const float*)d_in[11], (const float*)d_in[18]};
  const float* b_[3]  = {(const float*)d_in[5],  (const float*)d_in[12], (const float*)d_in[19]};
  const float* gw[3]  = {(const float*)d_in[6],  (const float*)d_in[13], (const float*)d_in[20]};
  const float* gb[3]  = {(const float*)d_in[7],  (const float*)d_in[14], (const float*)d_in[21]};
  const float* ga[3]  = {(const float*)d_in[8],  (const float*)d_in[15], (const float*)d_in[22]};
  const float* mW0 = (const float*)d_in[23];
  const float* mb0 = (const float*)d_in[24];
  const float* mW1 = (const float*)d_in[25];
  const float* mb1 = (const float*)d_in[26];
  const float* mW2 = (const float*)d_in[27];
  const float* mb2 = (const float*)d_in[28];
  float* out = (float*)d_out;

  char* ws = (char*)d_ws;
  size_t off = 0;
  auto take = [&](size_t bytes) -> char* {
    char* p = ws + off;
    off = (off + bytes + 255) & ~(size_t)255;
    return p;
  };
  ushort* xb    = (ushort*)take((size_t)NN * FDIM * 2);
  ushort* hb    = (ushort*)take((size_t)NN * FDIM * 2);
  ushort* yb    = (ushort*)take((size_t)NN * FDIM * 2);
  ushort* aggb  = (ushort*)take((size_t)NN * FDIM * 2);
  float* bufD   = (float*)take((size_t)NN * CC * 4);
  ushort* Wt[3];
  for (int i = 0; i < 3; i++) Wt[i] = (ushort*)take((size_t)256 * 256 * 2);
  float* s_arr  = (float*)take((size_t)NN * HH * 4);
  float* d_arr  = (float*)take((size_t)NN * HH * 4);
  int* deg      = (int*)take((size_t)NN * 4);
  int* cursor   = (int*)take((size_t)NN * 4);
  int* rowptr   = (int*)take((size_t)(NN + 1) * 4);
  int* csr_src  = (int*)take((size_t)ET * 4);
  int* bsum     = (int*)take(512);
  int* boff     = (int*)take(512);
  float* colsum   = (float*)take(1024);   // colsum+colsumsq contiguous: one memset
  float* colsumsq = (float*)take(1024);
  int* flag       = (int*)take(256);

  // CSR build (reused by all 3 layers)
  hipMemsetAsync(deg, 0, (size_t)NN * 4, stream);
  detect_kernel<<<1, 256, 0, stream>>>((const unsigned int*)ei, flag);
  degree_kernel<<<(ET + 255) / 256, 256, 0, stream>>>(ei, flag, deg);
  scan1_kernel<<<SCAN_NB, SCAN_BLK, 0, stream>>>(deg, rowptr, bsum);
  scan2_kernel<<<1, 128, 0, stream>>>(bsum, boff, rowptr);
  scan3_kernel<<<SCAN_NB, SCAN_BLK, 0, stream>>>(rowptr, cursor, boff);
  fill_kernel<<<(ET + 255) / 256, 256, 0, stream>>>(ei, flag, cursor, csr_src);

  // dtype prep
  conv_x_kernel<<<(NN * FDIM / 4 + 255) / 256, 256, 0, stream>>>(x, xb);
  for (int L = 0; L < 3; L++)
    conv_w_kernel<<<256, 256, 0, stream>>>(W[L], Wt[L]);

  const ushort* lin = xb;
  for (int L = 0; L < 3; L++) {
    gemm_bf16<<<dim3((NN + 127) / 128, 2), 256, 0, stream>>>(lin, Wt[L], hb);
    sd_kernel<<<NN / 4, 256, 0, stream>>>(hb, as_[L], ad_[L], s_arr, d_arr);
    hipMemsetAsync(colsum, 0, 2048, stream);
    if (L < 2) {
      agg_kernel<true><<<NN / 4, 256, 0, stream>>>(hb, s_arr, d_arr, rowptr, csr_src, b_[L], aggb);
      norm_reduce_bf<<<(NN + 127) / 128, 256, 0, stream>>>(aggb, colsum, colsumsq);
      norm_apply_bf<<<1024, 256, 0, stream>>>(aggb, yb, colsum, colsumsq, ga[L], gw[L], gb[L]);
      lin = yb;
    } else {
      agg_kernel<false><<<NN / 4, 256, 0, stream>>>(hb, s_arr, d_arr, rowptr, csr_src, b_[L], bufD);
      norm_reduce_f32<<<(NN + 127) / 128, 256, 0, stream>>>(bufD, colsum, colsumsq);
      norm_apply_f32<<<512, 256, 0, stream>>>(bufD, colsum, colsumsq, ga[L], gw[L], gb[L]);
    }
  }
  mlp_kernel<<<(NN + 255) / 256, 256, 0, stream>>>(bufD, mW0, mb0, mW1, mb1, mW2, mb2, out);
}